// Round 1
// 750.168 us; speedup vs baseline: 1.1176x; 1.1176x over previous
//
#include <hip/hip_runtime.h>
#include <hip/hip_bf16.h>

typedef unsigned short ushort_t;
typedef unsigned int uint_t;
typedef __attribute__((ext_vector_type(8))) short short8;
typedef __attribute__((ext_vector_type(4))) float float4v;

__device__ __forceinline__ float bf2f(ushort_t u) {
    union { uint_t i; float f; } c; c.i = ((uint_t)u) << 16; return c.f;
}
__device__ __forceinline__ ushort_t f2bf(float f) {
    union { float f; uint_t i; } c; c.f = f;
    uint_t x = c.i;
    uint_t r = x + 0x7fffu + ((x >> 16) & 1u);   // RNE
    return (ushort_t)(r >> 16);
}

// async global->LDS, 16B per lane; LDS dest = wave-uniform base + lane*16
__device__ __forceinline__ void gl_lds16(const void* g, void* l) {
    __builtin_amdgcn_global_load_lds(
        (const __attribute__((address_space(1))) void*)g,
        (__attribute__((address_space(3))) void*)l, 16, 0, 0);
}

__device__ __forceinline__ void stv(float* p, float v) { *p = v; }
__device__ __forceinline__ void stv(ushort_t* p, float v) { *p = f2bf(v); }

// ---------------- graph setup: counting sort by dst ----------------
__global__ void hist_kernel(const int* __restrict__ dstv, int* __restrict__ cnt, int E) {
    int e = blockIdx.x * 256 + threadIdx.x;
    if (e < E) atomicAdd(&cnt[dstv[e]], 1);
}

// one block, 1024 threads: chunked scan (PER<=16 -> n<=16384)
__global__ __launch_bounds__(1024) void scan_kernel(
    const int* __restrict__ cnt, int* __restrict__ rowptr,
    int* __restrict__ cursor, float* __restrict__ deginv, int n) {
    __shared__ int sums[1024];
    const int t = threadIdx.x;
    const int per = (n + 1023) >> 10;
    const int b0 = t * per;
    int s = 0;
    for (int u = 0; u < per; u++) {
        int i = b0 + u;
        if (i < n) s += cnt[i];
    }
    sums[t] = s;
    __syncthreads();
    int x = s;
    for (int off = 1; off < 1024; off <<= 1) {
        int y = (t >= off) ? sums[t - off] : 0;
        __syncthreads();
        x += y;
        sums[t] = x;
        __syncthreads();
    }
    int run = x - s;   // exclusive prefix of this thread's chunk
    for (int u = 0; u < per; u++) {
        int i = b0 + u;
        if (i < n) {
            int v = cnt[i];
            rowptr[i] = run;
            cursor[i] = run;
            deginv[i] = 1.0f / (float)(v > 0 ? v : 1);
            run += v;
        }
    }
    if (t == 1023) rowptr[n] = x;
}

__global__ void scatter_kernel(const int* __restrict__ srcv, const int* __restrict__ dstv,
                               int* __restrict__ cursor, int* __restrict__ srcs_sorted, int E) {
    int e = blockIdx.x * 256 + threadIdx.x;
    if (e < E) {
        int p = atomicAdd(&cursor[dstv[e]], 1);
        srcs_sorted[p] = srcv[e];
    }
}

// ---------------- weight transpose ----------------
// Generic (for s2, Nout=N): WT[i][k] = bf16(Wcat[k][i]); Wcat=[W0;W1], WT [Nout][256].
__global__ __launch_bounds__(256) void transpose_w_kernel(
    const float* __restrict__ W0, const float* __restrict__ W1,
    ushort_t* __restrict__ WT, int Nout) {
    __shared__ ushort_t tile[64][72];
    const int i0 = blockIdx.x * 64;
    const int k0 = blockIdx.y * 64;
    const float* W = (k0 < 128) ? (W0 + (size_t)k0 * Nout)
                                : (W1 + (size_t)(k0 - 128) * Nout);
    const int tid = threadIdx.x;
    const int li = tid & 63;
    const int kq = tid >> 6;
    const int gi = i0 + li;
    const bool ok = gi < Nout;
    for (int k = kq; k < 64; k += 4) {
        float v = ok ? W[(size_t)k * Nout + gi] : 0.f;
        tile[li][k] = f2bf(v);
    }
    __syncthreads();
    for (int s = tid; s < 512; s += 256) {
        int r = s >> 3, ch = s & 7;
        int gi2 = i0 + r;
        if (gi2 < Nout)
            *(short8*)(WT + (size_t)gi2 * 256 + k0 + ch * 8) = *(const short8*)&tile[r][ch * 8];
    }
}

// Batched transpose for the 5 square (Nout=128) layers in ONE launch.
struct W5 { const float* W0[5]; const float* W1[5]; };
__global__ __launch_bounds__(256) void transpose_w5_kernel(W5 wp, ushort_t* __restrict__ WT) {
    __shared__ ushort_t tile[64][72];
    const int layer = blockIdx.z;
    const int i0 = blockIdx.x * 64;            // 0 or 64
    const int k0 = blockIdx.y * 64;            // 0,64,128,192
    const float* W = (k0 < 128) ? (wp.W0[layer] + (size_t)k0 * 128)
                                : (wp.W1[layer] + (size_t)(k0 - 128) * 128);
    ushort_t* WTb = WT + (size_t)layer * 128 * 256;
    const int tid = threadIdx.x;
    const int li = tid & 63;
    const int kq = tid >> 6;
    const int gi = i0 + li;
    for (int k = kq; k < 64; k += 4)
        tile[li][k] = f2bf(W[(size_t)k * 128 + gi]);
    __syncthreads();
    for (int s = tid; s < 512; s += 256) {
        int r = s >> 3, ch = s & 7;
        *(short8*)(WTb + (size_t)(i0 + r) * 256 + k0 + ch * 8) = *(const short8*)&tile[r][ch * 8];
    }
}

// ---------------- aggregation (wave per node) ----------------
// Acat[n][0:128] = bf16(mean of act[src]); Acat[n][128:256] = bf16(act[n])
template <typename TIN>
__device__ __forceinline__ float2 ld2(const TIN* act, size_t row, int t);
template <>
__device__ __forceinline__ float2 ld2<float>(const float* act, size_t row, int t) {
    return ((const float2*)act)[row * 64 + t];
}
template <>
__device__ __forceinline__ float2 ld2<ushort_t>(const ushort_t* act, size_t row, int t) {
    uint_t u = ((const uint_t*)act)[row * 64 + t];
    float2 r; r.x = bf2f((ushort_t)(u & 0xffffu)); r.y = bf2f((ushort_t)(u >> 16));
    return r;
}

template <typename TIN>
__global__ __launch_bounds__(256) void aggregate_kernel(
    const TIN* __restrict__ act, const int* __restrict__ srcs,
    const int* __restrict__ rowptr, const float* __restrict__ deginv,
    ushort_t* __restrict__ Acat, int N) {
    int node = blockIdx.x * 4 + (threadIdx.x >> 6);
    if (node >= N) return;
    int t = threadIdx.x & 63;
    int e0 = rowptr[node], e1 = rowptr[node + 1];
    float ax = 0.f, ay = 0.f;
    int e = e0;
    for (; e + 4 <= e1; e += 4) {
        int s0 = srcs[e], s1 = srcs[e + 1], s2 = srcs[e + 2], s3 = srcs[e + 3];
        float2 v0 = ld2(act, (size_t)s0, t);
        float2 v1 = ld2(act, (size_t)s1, t);
        float2 v2 = ld2(act, (size_t)s2, t);
        float2 v3 = ld2(act, (size_t)s3, t);
        ax += v0.x + v1.x + v2.x + v3.x;
        ay += v0.y + v1.y + v2.y + v3.y;
    }
    for (; e < e1; e++) {
        float2 v = ld2(act, (size_t)srcs[e], t);
        ax += v.x; ay += v.y;
    }
    float dinv = deginv[node];
    uint_t m = ((uint_t)f2bf(ay * dinv) << 16) | (uint_t)f2bf(ax * dinv);
    float2 self = ld2(act, (size_t)node, t);
    uint_t sf = ((uint_t)f2bf(self.y) << 16) | (uint_t)f2bf(self.x);
    ((uint_t*)Acat)[(size_t)node * 128 + t]      = m;
    ((uint_t*)Acat)[(size_t)node * 128 + 64 + t] = sf;
}

// Fused aggregate over a [N][256] bf16 activation (a-half cols 0:128, s-half 128:256):
// ONE gather pass produces AcatA (from a-half) and AcatS (from s-half).
__global__ __launch_bounds__(256) void aggregate2_kernel(
    const ushort_t* __restrict__ act, const int* __restrict__ srcs,
    const int* __restrict__ rowptr, const float* __restrict__ deginv,
    ushort_t* __restrict__ AcatA, ushort_t* __restrict__ AcatS, int N) {
    int node = blockIdx.x * 4 + (threadIdx.x >> 6);
    if (node >= N) return;
    int t = threadIdx.x & 63;
    const uint_t* A = (const uint_t*)act;
    int e0 = rowptr[node], e1 = rowptr[node + 1];
    float ax = 0.f, ay = 0.f, sx = 0.f, sy = 0.f;
    int e = e0;
    for (; e + 2 <= e1; e += 2) {
        size_t r0 = (size_t)srcs[e] * 128, r1 = (size_t)srcs[e + 1] * 128;
        uint_t ua0 = A[r0 + t], us0 = A[r0 + 64 + t];
        uint_t ua1 = A[r1 + t], us1 = A[r1 + 64 + t];
        ax += bf2f((ushort_t)(ua0 & 0xffffu)) + bf2f((ushort_t)(ua1 & 0xffffu));
        ay += bf2f((ushort_t)(ua0 >> 16))     + bf2f((ushort_t)(ua1 >> 16));
        sx += bf2f((ushort_t)(us0 & 0xffffu)) + bf2f((ushort_t)(us1 & 0xffffu));
        sy += bf2f((ushort_t)(us0 >> 16))     + bf2f((ushort_t)(us1 >> 16));
    }
    if (e < e1) {
        size_t r0 = (size_t)srcs[e] * 128;
        uint_t ua0 = A[r0 + t], us0 = A[r0 + 64 + t];
        ax += bf2f((ushort_t)(ua0 & 0xffffu));
        ay += bf2f((ushort_t)(ua0 >> 16));
        sx += bf2f((ushort_t)(us0 & 0xffffu));
        sy += bf2f((ushort_t)(us0 >> 16));
    }
    float dinv = deginv[node];
    size_t rb = (size_t)node * 128;
    uint_t sa = A[rb + t], ss = A[rb + 64 + t];   // self rows already bf16
    ((uint_t*)AcatA)[rb + t]      = ((uint_t)f2bf(ay * dinv) << 16) | (uint_t)f2bf(ax * dinv);
    ((uint_t*)AcatA)[rb + 64 + t] = sa;
    ((uint_t*)AcatS)[rb + t]      = ((uint_t)f2bf(sy * dinv) << 16) | (uint_t)f2bf(sx * dinv);
    ((uint_t*)AcatS)[rb + 64 + t] = ss;
}

// ---------------- NT GEMM: C[i][j] = relu(sum_k A[i][k]*B[j][k] + bias) ----------------
// A:[rowsA][256] bf16, B:[rowsB][256] bf16, C:[rowsA][rowsB] (ldc=rowsB).
// bias indexed by i (BIAS_I) or j (with optional second vector bias2 for j>=jsplit).
// SWZ: 2-D 8x8 supergroups (1 MB L2 working set) + bijective XCD chunking; grid
//      must be tM8*tN8*64. Non-SWZ: exact grid tilesM*tilesN, GRP=8 M-grouping.
template <bool BIAS_I, bool SWZ, typename TOUT>
__global__ __launch_bounds__(256) void gemm_nt_kernel(
    const ushort_t* __restrict__ A, const ushort_t* __restrict__ B,
    const float* __restrict__ bias, const float* __restrict__ bias2, int jsplit,
    TOUT* __restrict__ C, int rowsA, int rowsB, int tilesM, int tilesN) {
    __shared__ __align__(16) ushort_t Alds[128 * 64];
    __shared__ __align__(16) ushort_t Blds[128 * 64];

    int pid_m, pid_n;
    if (SWZ) {
        const int lin = blockIdx.x;
        const int nwg = gridDim.x;                 // multiple of 64 -> %8==0
        const int w = (lin & 7) * (nwg >> 3) + (lin >> 3);   // XCD chunk (bijective)
        const int tM8 = (tilesM + 7) >> 3;
        const int sg = w >> 6, is = w & 63;        // 8x8 supergroup
        const int sgm = sg % tM8, sgn = sg / tM8;
        pid_m = sgm * 8 + (is & 7);
        pid_n = sgn * 8 + (is >> 3);
        if (pid_m >= tilesM || pid_n >= tilesN) return;   // block-uniform exit
    } else {
        const int lin = blockIdx.x;
        const int GRP = 8;
        const int nig = GRP * tilesN;
        const int gidg = lin / nig;
        const int first_m = gidg * GRP;
        const int gsz = min(tilesM - first_m, GRP);
        const int in_grp = lin - gidg * nig;
        pid_m = first_m + (in_grp % gsz);
        pid_n = in_grp / gsz;
    }
    const int i0 = pid_m * 128;
    const int j0 = pid_n * 128;

    const int tid  = threadIdx.x;
    const int lane = tid & 63;
    const int wid  = tid >> 6;
    const int wm = wid >> 1, wn = wid & 1;
    const int r16 = lane & 15, quad = lane >> 4;
    const int rsub = lane >> 3;              // row-in-window 0..7
    const int csw  = (lane & 7) ^ rsub;      // swizzled global chunk for staging

    float4v acc[4][4];
#pragma unroll
    for (int a = 0; a < 4; a++)
#pragma unroll
        for (int b = 0; b < 4; b++) acc[a][b] = (float4v){0.f, 0.f, 0.f, 0.f};

    for (int kt = 0; kt < 4; kt++) {
        __syncthreads();
        const int kbase = kt * 64 + csw * 8;
#pragma unroll
        for (int t = 0; t < 4; t++) {
            const int w8 = (wid * 4 + t) * 8;     // first row of this 8-row window
            int rA = min(i0 + w8 + rsub, rowsA - 1);
            gl_lds16(A + (size_t)rA * 256 + kbase, Alds + w8 * 64);
            int rB = min(j0 + w8 + rsub, rowsB - 1);
            gl_lds16(B + (size_t)rB * 256 + kbase, Blds + w8 * 64);
        }
        __syncthreads();   // barrier drains vmcnt -> LDS tiles ready
#pragma unroll
        for (int ks = 0; ks < 2; ks++) {
            const int chb = ks * 4 + quad;
            const int sw = ((chb ^ (r16 & 7))) * 8;
            short8 af[4], bfr[4];
#pragma unroll
            for (int im = 0; im < 4; im++)
                af[im] = *(const short8*)(Alds + (wm * 64 + im * 16 + r16) * 64 + sw);
#pragma unroll
            for (int jn = 0; jn < 4; jn++)
                bfr[jn] = *(const short8*)(Blds + (wn * 64 + jn * 16 + r16) * 64 + sw);
#pragma unroll
            for (int im = 0; im < 4; im++)
#pragma unroll
                for (int jn = 0; jn < 4; jn++)
                    acc[im][jn] = __builtin_amdgcn_mfma_f32_16x16x32_bf16(
                        af[im], bfr[jn], acc[im][jn], 0, 0, 0);
        }
    }

    const int rows_lim = rowsA - i0;
    const int cols_lim = rowsB - j0;
#pragma unroll
    for (int im = 0; im < 4; im++) {
#pragma unroll
        for (int jn = 0; jn < 4; jn++) {
            const int jl = wn * 64 + jn * 16 + r16;
            if (jl < cols_lim) {
                float bj = 0.f;
                if (!BIAS_I) {
                    int jg = j0 + jl;
                    bj = (jg >= jsplit) ? bias2[jg - jsplit] : bias[jg];
                }
#pragma unroll
                for (int r = 0; r < 4; r++) {
                    const int il = wm * 64 + im * 16 + quad * 4 + r;
                    if (il < rows_lim) {
                        float bv = BIAS_I ? bias[i0 + il] : bj;
                        float v = fmaxf(acc[im][jn][r] + bv, 0.f);
                        stv(C + (size_t)(i0 + il) * rowsB + (j0 + jl), v);
                    }
                }
            }
        }
    }
}

// ---------------- host launch ----------------
extern "C" void kernel_launch(void* const* d_in, const int* in_sizes, int n_in,
                              void* d_out, int out_size, void* d_ws, size_t ws_size,
                              hipStream_t stream) {
    const int N = in_sizes[18];       // bl_s2 length == num nodes
    const int E = in_sizes[1] / 2;

    const float* x = (const float*)d_in[0];
    const int* ei = (const int*)d_in[1];
    const int* srcv = ei;
    const int* dstv = ei + E;

    // layer order in inputs: e1, e2, a1, a2, s1, s2
    const float* Wl[6] = {(const float*)d_in[2],  (const float*)d_in[5],
                          (const float*)d_in[8],  (const float*)d_in[11],
                          (const float*)d_in[14], (const float*)d_in[17]};
    const float* bl[6] = {(const float*)d_in[3],  (const float*)d_in[6],
                          (const float*)d_in[9],  (const float*)d_in[12],
                          (const float*)d_in[15], (const float*)d_in[18]};
    const float* Wr[6] = {(const float*)d_in[4],  (const float*)d_in[7],
                          (const float*)d_in[10], (const float*)d_in[13],
                          (const float*)d_in[16], (const float*)d_in[19]};

    char* p = (char*)d_ws;
    auto carve = [&](size_t bytes) -> char* {
        char* q = p;
        p += (bytes + 255) & ~(size_t)255;
        return q;
    };
    int*      cnt    = (int*)carve((size_t)N * 4);
    int*      rowptr = (int*)carve((size_t)(N + 1) * 4);
    int*      cursor = (int*)carve((size_t)N * 4);
    float*    deginv = (float*)carve((size_t)N * 4);
    int*      srcs   = (int*)carve((size_t)E * 4);
    ushort_t* Acat   = (ushort_t*)carve((size_t)N * 256 * 2);
    ushort_t* AcatS  = (ushort_t*)carve((size_t)N * 256 * 2);
    ushort_t* hbA    = (ushort_t*)carve((size_t)N * 128 * 2);   // bf16 activations
    ushort_t* hbB    = (ushort_t*)carve((size_t)N * 128 * 2);
    ushort_t* hbC    = (ushort_t*)carve((size_t)N * 256 * 2);   // a1|s1 fused output
    ushort_t* WTs2   = (ushort_t*)carve((size_t)N * 256 * 2);   // s2 weights transposed
    ushort_t* WsT    = (ushort_t*)carve((size_t)5 * 128 * 256 * 2);

    hipMemsetAsync(cnt, 0, (size_t)N * 4, stream);
    hist_kernel<<<(E + 255) / 256, 256, 0, stream>>>(dstv, cnt, E);
    scan_kernel<<<1, 1024, 0, stream>>>(cnt, rowptr, cursor, deginv, N);
    scatter_kernel<<<(E + 255) / 256, 256, 0, stream>>>(srcv, dstv, cursor, srcs, E);

    // transpose the 5 square layers in WsT order [e1, e2, a1, s1, a2]
    // (a1 and s1 contiguous -> their GEMMs fuse into one 256-col GEMM)
    W5 w5;
    w5.W0[0] = Wl[0]; w5.W1[0] = Wr[0];   // e1
    w5.W0[1] = Wl[1]; w5.W1[1] = Wr[1];   // e2
    w5.W0[2] = Wl[2]; w5.W1[2] = Wr[2];   // a1
    w5.W0[3] = Wl[4]; w5.W1[3] = Wr[4];   // s1
    w5.W0[4] = Wl[3]; w5.W1[4] = Wr[3];   // a2
    transpose_w5_kernel<<<dim3(2, 4, 5), 256, 0, stream>>>(w5, WsT);
    transpose_w_kernel<<<dim3((N + 63) / 64, 4), 256, 0, stream>>>(
        Wl[5], Wr[5], WTs2, N);

    float* outp = (float*)d_out;
    float* xh_out = outp + (size_t)N * N;

    const int tM = (N + 127) / 128;       // 79
    const int BIG = 1 << 30;

    // e1: x(fp32) -> hbA
    aggregate_kernel<float><<<(N + 3) / 4, 256, 0, stream>>>(x, srcs, rowptr, deginv, Acat, N);
    gemm_nt_kernel<false, false, ushort_t><<<tM, 256, 0, stream>>>(
        Acat, WsT + 0 * 128 * 256, bl[0], nullptr, BIG, hbA, N, 128, tM, 1);
    // e2: hbA -> hbB (h)
    aggregate_kernel<ushort_t><<<(N + 3) / 4, 256, 0, stream>>>(hbA, srcs, rowptr, deginv, Acat, N);
    gemm_nt_kernel<false, false, ushort_t><<<tM, 256, 0, stream>>>(
        Acat, WsT + 1 * 128 * 256, bl[1], nullptr, BIG, hbB, N, 128, tM, 1);
    // a1+s1 fused: ONE aggregate of h, ONE GEMM with 256 output cols -> hbC
    aggregate_kernel<ushort_t><<<(N + 3) / 4, 256, 0, stream>>>(hbB, srcs, rowptr, deginv, Acat, N);
    gemm_nt_kernel<false, false, ushort_t><<<tM * 2, 256, 0, stream>>>(
        Acat, WsT + 2 * 128 * 256, bl[2], bl[4], 128, hbC, N, 256, tM, 2);
    // a2+s2 aggregates fused: one gather pass over hbC -> Acat (a-half), AcatS (s-half)
    aggregate2_kernel<<<(N + 3) / 4, 256, 0, stream>>>(hbC, srcs, rowptr, deginv, Acat, AcatS, N);
    // a2: -> xh (fp32, direct to d_out)
    gemm_nt_kernel<false, false, float><<<tM, 256, 0, stream>>>(
        Acat, WsT + 4 * 128 * 256, bl[3], nullptr, BIG, xh_out, N, 128, tM, 1);
    // s2: A = WTs2 (i over out-dim), B = AcatS (j over nodes), bias on i, C = s^T
    const int tM8 = (tM + 7) / 8;
    gemm_nt_kernel<true, true, float><<<tM8 * tM8 * 64, 256, 0, stream>>>(
        WTs2, AcatS, bl[5], nullptr, BIG, outp, N, N, tM, tM);

    (void)n_in; (void)out_size; (void)ws_size;
}

// Round 2
// 673.858 us; speedup vs baseline: 1.2442x; 1.1132x over previous
//
#include <hip/hip_runtime.h>
#include <hip/hip_bf16.h>

typedef unsigned short ushort_t;
typedef unsigned int uint_t;
typedef __attribute__((ext_vector_type(8))) short short8;
typedef __attribute__((ext_vector_type(4))) float float4v;

__device__ __forceinline__ float bf2f(ushort_t u) {
    union { uint_t i; float f; } c; c.i = ((uint_t)u) << 16; return c.f;
}
__device__ __forceinline__ ushort_t f2bf(float f) {
    union { float f; uint_t i; } c; c.f = f;
    uint_t x = c.i;
    uint_t r = x + 0x7fffu + ((x >> 16) & 1u);   // RNE
    return (ushort_t)(r >> 16);
}

// async global->LDS, 16B per lane; LDS dest = wave-uniform base + lane*16
__device__ __forceinline__ void gl_lds16(const void* g, void* l) {
    __builtin_amdgcn_global_load_lds(
        (const __attribute__((address_space(1))) void*)g,
        (__attribute__((address_space(3))) void*)l, 16, 0, 0);
}

__device__ __forceinline__ void stv(float* p, float v) { *p = v; }
__device__ __forceinline__ void stv(ushort_t* p, float v) { *p = f2bf(v); }

// ---------------- graph setup: counting sort by dst ----------------
__global__ void hist_kernel(const int* __restrict__ dstv, int* __restrict__ cnt, int E) {
    int e = blockIdx.x * 256 + threadIdx.x;
    if (e < E) atomicAdd(&cnt[dstv[e]], 1);
}

// one block, 1024 threads: chunked scan (PER<=16 -> n<=16384)
__global__ __launch_bounds__(1024) void scan_kernel(
    const int* __restrict__ cnt, int* __restrict__ rowptr,
    int* __restrict__ cursor, float* __restrict__ deginv, int n) {
    __shared__ int sums[1024];
    const int t = threadIdx.x;
    const int per = (n + 1023) >> 10;
    const int b0 = t * per;
    int s = 0;
    for (int u = 0; u < per; u++) {
        int i = b0 + u;
        if (i < n) s += cnt[i];
    }
    sums[t] = s;
    __syncthreads();
    int x = s;
    for (int off = 1; off < 1024; off <<= 1) {
        int y = (t >= off) ? sums[t - off] : 0;
        __syncthreads();
        x += y;
        sums[t] = x;
        __syncthreads();
    }
    int run = x - s;   // exclusive prefix of this thread's chunk
    for (int u = 0; u < per; u++) {
        int i = b0 + u;
        if (i < n) {
            int v = cnt[i];
            rowptr[i] = run;
            cursor[i] = run;
            deginv[i] = 1.0f / (float)(v > 0 ? v : 1);
            run += v;
        }
    }
    if (t == 1023) rowptr[n] = x;
}

__global__ void scatter_kernel(const int* __restrict__ srcv, const int* __restrict__ dstv,
                               int* __restrict__ cursor, int* __restrict__ srcs_sorted, int E) {
    int e = blockIdx.x * 256 + threadIdx.x;
    if (e < E) {
        int p = atomicAdd(&cursor[dstv[e]], 1);
        srcs_sorted[p] = srcv[e];
    }
}

// ---------------- weight transpose ----------------
// Generic (for s2, Nout=N): WT[i][k] = bf16(Wcat[k][i]); Wcat=[W0;W1], WT [Nout][256].
__global__ __launch_bounds__(256) void transpose_w_kernel(
    const float* __restrict__ W0, const float* __restrict__ W1,
    ushort_t* __restrict__ WT, int Nout) {
    __shared__ ushort_t tile[64][72];
    const int i0 = blockIdx.x * 64;
    const int k0 = blockIdx.y * 64;
    const float* W = (k0 < 128) ? (W0 + (size_t)k0 * Nout)
                                : (W1 + (size_t)(k0 - 128) * Nout);
    const int tid = threadIdx.x;
    const int li = tid & 63;
    const int kq = tid >> 6;
    const int gi = i0 + li;
    const bool ok = gi < Nout;
    for (int k = kq; k < 64; k += 4) {
        float v = ok ? W[(size_t)k * Nout + gi] : 0.f;
        tile[li][k] = f2bf(v);
    }
    __syncthreads();
    for (int s = tid; s < 512; s += 256) {
        int r = s >> 3, ch = s & 7;
        int gi2 = i0 + r;
        if (gi2 < Nout)
            *(short8*)(WT + (size_t)gi2 * 256 + k0 + ch * 8) = *(const short8*)&tile[r][ch * 8];
    }
}

// Batched transpose for the 5 square (Nout=128) layers in ONE launch.
struct W5 { const float* W0[5]; const float* W1[5]; };
__global__ __launch_bounds__(256) void transpose_w5_kernel(W5 wp, ushort_t* __restrict__ WT) {
    __shared__ ushort_t tile[64][72];
    const int layer = blockIdx.z;
    const int i0 = blockIdx.x * 64;            // 0 or 64
    const int k0 = blockIdx.y * 64;            // 0,64,128,192
    const float* W = (k0 < 128) ? (wp.W0[layer] + (size_t)k0 * 128)
                                : (wp.W1[layer] + (size_t)(k0 - 128) * 128);
    ushort_t* WTb = WT + (size_t)layer * 128 * 256;
    const int tid = threadIdx.x;
    const int li = tid & 63;
    const int kq = tid >> 6;
    const int gi = i0 + li;
    for (int k = kq; k < 64; k += 4)
        tile[li][k] = f2bf(W[(size_t)k * 128 + gi]);
    __syncthreads();
    for (int s = tid; s < 512; s += 256) {
        int r = s >> 3, ch = s & 7;
        *(short8*)(WTb + (size_t)(i0 + r) * 256 + k0 + ch * 8) = *(const short8*)&tile[r][ch * 8];
    }
}

// ---------------- aggregation (wave per node) ----------------
// Acat[n][0:128] = bf16(mean of act[src]); Acat[n][128:256] = bf16(act[n])
template <typename TIN>
__device__ __forceinline__ float2 ld2(const TIN* act, size_t row, int t);
template <>
__device__ __forceinline__ float2 ld2<float>(const float* act, size_t row, int t) {
    return ((const float2*)act)[row * 64 + t];
}
template <>
__device__ __forceinline__ float2 ld2<ushort_t>(const ushort_t* act, size_t row, int t) {
    uint_t u = ((const uint_t*)act)[row * 64 + t];
    float2 r; r.x = bf2f((ushort_t)(u & 0xffffu)); r.y = bf2f((ushort_t)(u >> 16));
    return r;
}

template <typename TIN>
__global__ __launch_bounds__(256) void aggregate_kernel(
    const TIN* __restrict__ act, const int* __restrict__ srcs,
    const int* __restrict__ rowptr, const float* __restrict__ deginv,
    ushort_t* __restrict__ Acat, int N) {
    int node = blockIdx.x * 4 + (threadIdx.x >> 6);
    if (node >= N) return;
    int t = threadIdx.x & 63;
    int e0 = rowptr[node], e1 = rowptr[node + 1];
    float ax = 0.f, ay = 0.f;
    int e = e0;
    for (; e + 4 <= e1; e += 4) {
        int s0 = srcs[e], s1 = srcs[e + 1], s2 = srcs[e + 2], s3 = srcs[e + 3];
        float2 v0 = ld2(act, (size_t)s0, t);
        float2 v1 = ld2(act, (size_t)s1, t);
        float2 v2 = ld2(act, (size_t)s2, t);
        float2 v3 = ld2(act, (size_t)s3, t);
        ax += v0.x + v1.x + v2.x + v3.x;
        ay += v0.y + v1.y + v2.y + v3.y;
    }
    for (; e < e1; e++) {
        float2 v = ld2(act, (size_t)srcs[e], t);
        ax += v.x; ay += v.y;
    }
    float dinv = deginv[node];
    uint_t m = ((uint_t)f2bf(ay * dinv) << 16) | (uint_t)f2bf(ax * dinv);
    float2 self = ld2(act, (size_t)node, t);
    uint_t sf = ((uint_t)f2bf(self.y) << 16) | (uint_t)f2bf(self.x);
    ((uint_t*)Acat)[(size_t)node * 128 + t]      = m;
    ((uint_t*)Acat)[(size_t)node * 128 + 64 + t] = sf;
}

// Fused aggregate over a [N][256] bf16 activation (a-half cols 0:128, s-half 128:256):
// ONE gather pass produces AcatA (from a-half) and AcatS (from s-half).
__global__ __launch_bounds__(256) void aggregate2_kernel(
    const ushort_t* __restrict__ act, const int* __restrict__ srcs,
    const int* __restrict__ rowptr, const float* __restrict__ deginv,
    ushort_t* __restrict__ AcatA, ushort_t* __restrict__ AcatS, int N) {
    int node = blockIdx.x * 4 + (threadIdx.x >> 6);
    if (node >= N) return;
    int t = threadIdx.x & 63;
    const uint_t* A = (const uint_t*)act;
    int e0 = rowptr[node], e1 = rowptr[node + 1];
    float ax = 0.f, ay = 0.f, sx = 0.f, sy = 0.f;
    int e = e0;
    for (; e + 4 <= e1; e += 4) {
        size_t r0 = (size_t)srcs[e] * 128,     r1 = (size_t)srcs[e + 1] * 128;
        size_t r2 = (size_t)srcs[e + 2] * 128, r3 = (size_t)srcs[e + 3] * 128;
        uint_t ua0 = A[r0 + t], us0 = A[r0 + 64 + t];
        uint_t ua1 = A[r1 + t], us1 = A[r1 + 64 + t];
        uint_t ua2 = A[r2 + t], us2 = A[r2 + 64 + t];
        uint_t ua3 = A[r3 + t], us3 = A[r3 + 64 + t];
        ax += bf2f((ushort_t)(ua0 & 0xffffu)) + bf2f((ushort_t)(ua1 & 0xffffu))
            + bf2f((ushort_t)(ua2 & 0xffffu)) + bf2f((ushort_t)(ua3 & 0xffffu));
        ay += bf2f((ushort_t)(ua0 >> 16))     + bf2f((ushort_t)(ua1 >> 16))
            + bf2f((ushort_t)(ua2 >> 16))     + bf2f((ushort_t)(ua3 >> 16));
        sx += bf2f((ushort_t)(us0 & 0xffffu)) + bf2f((ushort_t)(us1 & 0xffffu))
            + bf2f((ushort_t)(us2 & 0xffffu)) + bf2f((ushort_t)(us3 & 0xffffu));
        sy += bf2f((ushort_t)(us0 >> 16))     + bf2f((ushort_t)(us1 >> 16))
            + bf2f((ushort_t)(us2 >> 16))     + bf2f((ushort_t)(us3 >> 16));
    }
    for (; e < e1; e++) {
        size_t r0 = (size_t)srcs[e] * 128;
        uint_t ua0 = A[r0 + t], us0 = A[r0 + 64 + t];
        ax += bf2f((ushort_t)(ua0 & 0xffffu));
        ay += bf2f((ushort_t)(ua0 >> 16));
        sx += bf2f((ushort_t)(us0 & 0xffffu));
        sy += bf2f((ushort_t)(us0 >> 16));
    }
    float dinv = deginv[node];
    size_t rb = (size_t)node * 128;
    uint_t sa = A[rb + t], ss = A[rb + 64 + t];   // self rows already bf16
    ((uint_t*)AcatA)[rb + t]      = ((uint_t)f2bf(ay * dinv) << 16) | (uint_t)f2bf(ax * dinv);
    ((uint_t*)AcatA)[rb + 64 + t] = sa;
    ((uint_t*)AcatS)[rb + t]      = ((uint_t)f2bf(sy * dinv) << 16) | (uint_t)f2bf(sx * dinv);
    ((uint_t*)AcatS)[rb + 64 + t] = ss;
}

// ---------------- NT GEMM: C[i][j] = relu(sum_k A[i][k]*B[j][k] + bias) ----------------
// A:[rowsA][256] bf16, B:[rowsB][256] bf16, C:[rowsA][rowsB] (ldc=rowsB).
// bias indexed by i (BIAS_I) or j (with optional second vector bias2 for j>=jsplit).
// TM in {128, 64}: output tile TM x 128, 4 waves (2x2), wave tile (TM/2) x 64.
// SWZ: 2-D 8x8 supergroups + bijective XCD chunking; grid must be tM8*tN8*64.
// Non-SWZ: exact grid tilesM*tilesN, GRP=8 M-grouping.
// fp32 output uses an LDS-transposed epilogue (coalesced dwordx4 stores).
template <bool BIAS_I, bool SWZ, int TM, typename TOUT>
__global__ __launch_bounds__(256) void gemm_nt_kernel(
    const ushort_t* __restrict__ A, const ushort_t* __restrict__ B,
    const float* __restrict__ bias, const float* __restrict__ bias2, int jsplit,
    TOUT* __restrict__ C, int rowsA, int rowsB, int tilesM, int tilesN) {
    constexpr int IMN = TM / 32;               // A-fragments per wave (4 or 2)
    // stage area: A tile TM*64 bf16 + B tile 128*64 bf16; fp32 epilogue reuses it
    __shared__ __align__(16) char smem[TM * 128 + 16384];
    ushort_t* Alds = (ushort_t*)smem;
    ushort_t* Blds = (ushort_t*)(smem + TM * 128);

    int pid_m, pid_n;
    if (SWZ) {
        const int lin = blockIdx.x;
        const int nwg = gridDim.x;                 // multiple of 64 -> %8==0
        const int w = (lin & 7) * (nwg >> 3) + (lin >> 3);   // XCD chunk (bijective)
        const int tM8 = (tilesM + 7) >> 3;
        const int sg = w >> 6, is = w & 63;        // 8x8 supergroup
        const int sgm = sg % tM8, sgn = sg / tM8;
        pid_m = sgm * 8 + (is & 7);
        pid_n = sgn * 8 + (is >> 3);
        if (pid_m >= tilesM || pid_n >= tilesN) return;   // block-uniform exit
    } else {
        const int lin = blockIdx.x;
        const int GRP = 8;
        const int nig = GRP * tilesN;
        const int gidg = lin / nig;
        const int first_m = gidg * GRP;
        const int gsz = min(tilesM - first_m, GRP);
        const int in_grp = lin - gidg * nig;
        pid_m = first_m + (in_grp % gsz);
        pid_n = in_grp / gsz;
    }
    const int i0 = pid_m * TM;
    const int j0 = pid_n * 128;

    const int tid  = threadIdx.x;
    const int lane = tid & 63;
    const int wid  = tid >> 6;
    const int wm = wid >> 1, wn = wid & 1;
    const int r16 = lane & 15, quad = lane >> 4;
    const int rsub = lane >> 3;              // row-in-window 0..7
    const int csw  = (lane & 7) ^ rsub;      // swizzled global chunk for staging

    float4v acc[IMN][4];
#pragma unroll
    for (int a = 0; a < IMN; a++)
#pragma unroll
        for (int b = 0; b < 4; b++) acc[a][b] = (float4v){0.f, 0.f, 0.f, 0.f};

    for (int kt = 0; kt < 4; kt++) {
        __syncthreads();
        const int kbase = kt * 64 + csw * 8;
#pragma unroll
        for (int t = 0; t < IMN; t++) {          // A: TM rows = IMN windows/wave
            const int w8 = (wid * IMN + t) * 8;
            int rA = min(i0 + w8 + rsub, rowsA - 1);
            gl_lds16(A + (size_t)rA * 256 + kbase, Alds + w8 * 64);
        }
#pragma unroll
        for (int t = 0; t < 4; t++) {            // B: 128 rows = 4 windows/wave
            const int w8 = (wid * 4 + t) * 8;
            int rB = min(j0 + w8 + rsub, rowsB - 1);
            gl_lds16(B + (size_t)rB * 256 + kbase, Blds + w8 * 64);
        }
        __syncthreads();   // barrier drains vmcnt -> LDS tiles ready
#pragma unroll
        for (int ks = 0; ks < 2; ks++) {
            const int chb = ks * 4 + quad;
            const int sw = ((chb ^ (r16 & 7))) * 8;
            short8 af[IMN], bfr[4];
#pragma unroll
            for (int im = 0; im < IMN; im++)
                af[im] = *(const short8*)(Alds + (wm * (TM / 2) + im * 16 + r16) * 64 + sw);
#pragma unroll
            for (int jn = 0; jn < 4; jn++)
                bfr[jn] = *(const short8*)(Blds + (wn * 64 + jn * 16 + r16) * 64 + sw);
#pragma unroll
            for (int im = 0; im < IMN; im++)
#pragma unroll
                for (int jn = 0; jn < 4; jn++)
                    acc[im][jn] = __builtin_amdgcn_mfma_f32_16x16x32_bf16(
                        af[im], bfr[jn], acc[im][jn], 0, 0, 0);
        }
    }

    const int rows_lim = rowsA - i0;
    const int cols_lim = rowsB - j0;

    if constexpr (sizeof(TOUT) == 4) {
        // ---- fp32: LDS-transposed epilogue, 32-row chunks, pitch 132 (2-way=free) ----
        float* T = (float*)smem;                 // 32*132*4 = 16896 B <= stage area
        constexpr int NCH = TM / 32;
#pragma unroll
        for (int c = 0; c < NCH; c++) {
            const int crow = c * 32;
            __syncthreads();                     // LDS free (stage reads / prev stores done)
            if (wm == crow / (TM / 2)) {
                const int imb = (crow - wm * (TM / 2)) / 16;
#pragma unroll
                for (int ii = 0; ii < 2; ii++) {
                    const int im = imb + ii;
#pragma unroll
                    for (int jn = 0; jn < 4; jn++) {
                        const int jl = wn * 64 + jn * 16 + r16;
                        float bj = 0.f;
                        if (!BIAS_I) {
                            int jg = j0 + jl;
                            bj = (jg >= jsplit) ? bias2[jg - jsplit] : bias[jg];
                        }
#pragma unroll
                        for (int r = 0; r < 4; r++) {
                            const int rl = ii * 16 + quad * 4 + r;
                            float bv = BIAS_I ? bias[min(i0 + crow + rl, rowsA - 1)] : bj;
                            T[rl * 132 + jl] = fmaxf(acc[im][jn][r] + bv, 0.f);
                        }
                    }
                }
            }
            __syncthreads();
            const int c4 = tid & 31, rl0 = tid >> 5;
#pragma unroll
            for (int s = 0; s < 4; s++) {
                const int rl = rl0 + s * 8;
                const int il = crow + rl;
                if (il < rows_lim) {
                    const int jl = c4 * 4;
                    float* dst = (float*)C + (size_t)(i0 + il) * rowsB + j0 + jl;
                    if (jl + 4 <= cols_lim) {
                        *(float4v*)dst = *(const float4v*)&T[rl * 132 + jl];
                    } else {
                        for (int jj = 0; jj < 4; jj++)
                            if (jl + jj < cols_lim) dst[jj] = T[rl * 132 + jl + jj];
                    }
                }
            }
        }
    } else {
        // ---- bf16: direct scalar stores (small outputs) ----
#pragma unroll
        for (int im = 0; im < IMN; im++) {
#pragma unroll
            for (int jn = 0; jn < 4; jn++) {
                const int jl = wn * 64 + jn * 16 + r16;
                if (jl < cols_lim) {
                    float bj = 0.f;
                    if (!BIAS_I) {
                        int jg = j0 + jl;
                        bj = (jg >= jsplit) ? bias2[jg - jsplit] : bias[jg];
                    }
#pragma unroll
                    for (int r = 0; r < 4; r++) {
                        const int il = wm * (TM / 2) + im * 16 + quad * 4 + r;
                        if (il < rows_lim) {
                            float bv = BIAS_I ? bias[i0 + il] : bj;
                            float v = fmaxf(acc[im][jn][r] + bv, 0.f);
                            stv(C + (size_t)(i0 + il) * rowsB + (j0 + jl), v);
                        }
                    }
                }
            }
        }
    }
}

// ---------------- host launch ----------------
extern "C" void kernel_launch(void* const* d_in, const int* in_sizes, int n_in,
                              void* d_out, int out_size, void* d_ws, size_t ws_size,
                              hipStream_t stream) {
    const int N = in_sizes[18];       // bl_s2 length == num nodes
    const int E = in_sizes[1] / 2;

    const float* x = (const float*)d_in[0];
    const int* ei = (const int*)d_in[1];
    const int* srcv = ei;
    const int* dstv = ei + E;

    // layer order in inputs: e1, e2, a1, a2, s1, s2
    const float* Wl[6] = {(const float*)d_in[2],  (const float*)d_in[5],
                          (const float*)d_in[8],  (const float*)d_in[11],
                          (const float*)d_in[14], (const float*)d_in[17]};
    const float* bl[6] = {(const float*)d_in[3],  (const float*)d_in[6],
                          (const float*)d_in[9],  (const float*)d_in[12],
                          (const float*)d_in[15], (const float*)d_in[18]};
    const float* Wr[6] = {(const float*)d_in[4],  (const float*)d_in[7],
                          (const float*)d_in[10], (const float*)d_in[13],
                          (const float*)d_in[16], (const float*)d_in[19]};

    char* p = (char*)d_ws;
    auto carve = [&](size_t bytes) -> char* {
        char* q = p;
        p += (bytes + 255) & ~(size_t)255;
        return q;
    };
    int*      cnt    = (int*)carve((size_t)N * 4);
    int*      rowptr = (int*)carve((size_t)(N + 1) * 4);
    int*      cursor = (int*)carve((size_t)N * 4);
    float*    deginv = (float*)carve((size_t)N * 4);
    int*      srcs   = (int*)carve((size_t)E * 4);
    ushort_t* Acat   = (ushort_t*)carve((size_t)N * 256 * 2);
    ushort_t* AcatS  = (ushort_t*)carve((size_t)N * 256 * 2);
    ushort_t* hbA    = (ushort_t*)carve((size_t)N * 128 * 2);   // bf16 activations
    ushort_t* hbB    = (ushort_t*)carve((size_t)N * 128 * 2);
    ushort_t* hbC    = (ushort_t*)carve((size_t)N * 256 * 2);   // a1|s1 fused output
    ushort_t* WTs2   = (ushort_t*)carve((size_t)N * 256 * 2);   // s2 weights transposed
    ushort_t* WsT    = (ushort_t*)carve((size_t)5 * 128 * 256 * 2);

    hipMemsetAsync(cnt, 0, (size_t)N * 4, stream);
    hist_kernel<<<(E + 255) / 256, 256, 0, stream>>>(dstv, cnt, E);
    scan_kernel<<<1, 1024, 0, stream>>>(cnt, rowptr, cursor, deginv, N);
    scatter_kernel<<<(E + 255) / 256, 256, 0, stream>>>(srcv, dstv, cursor, srcs, E);

    // transpose the 5 square layers in WsT order [e1, e2, a1, s1, a2]
    // (a1 and s1 contiguous -> their GEMMs fuse into one 256-col GEMM)
    W5 w5;
    w5.W0[0] = Wl[0]; w5.W1[0] = Wr[0];   // e1
    w5.W0[1] = Wl[1]; w5.W1[1] = Wr[1];   // e2
    w5.W0[2] = Wl[2]; w5.W1[2] = Wr[2];   // a1
    w5.W0[3] = Wl[4]; w5.W1[3] = Wr[4];   // s1
    w5.W0[4] = Wl[3]; w5.W1[4] = Wr[3];   // a2
    transpose_w5_kernel<<<dim3(2, 4, 5), 256, 0, stream>>>(w5, WsT);
    transpose_w_kernel<<<dim3((N + 63) / 64, 4), 256, 0, stream>>>(
        Wl[5], Wr[5], WTs2, N);

    float* outp = (float*)d_out;
    float* xh_out = outp + (size_t)N * N;

    const int tM128 = (N + 127) / 128;    // 79  (s2 tiles)
    const int tM64  = (N + 63) / 64;      // 157 (small-GEMM tiles)
    const int BIG = 1 << 30;

    // e1: x(fp32) -> hbA
    aggregate_kernel<float><<<(N + 3) / 4, 256, 0, stream>>>(x, srcs, rowptr, deginv, Acat, N);
    gemm_nt_kernel<false, false, 64, ushort_t><<<tM64, 256, 0, stream>>>(
        Acat, WsT + 0 * 128 * 256, bl[0], nullptr, BIG, hbA, N, 128, tM64, 1);
    // e2: hbA -> hbB (h)
    aggregate_kernel<ushort_t><<<(N + 3) / 4, 256, 0, stream>>>(hbA, srcs, rowptr, deginv, Acat, N);
    gemm_nt_kernel<false, false, 64, ushort_t><<<tM64, 256, 0, stream>>>(
        Acat, WsT + 1 * 128 * 256, bl[1], nullptr, BIG, hbB, N, 128, tM64, 1);
    // a1+s1 fused: ONE aggregate of h, ONE GEMM with 256 output cols -> hbC
    aggregate_kernel<ushort_t><<<(N + 3) / 4, 256, 0, stream>>>(hbB, srcs, rowptr, deginv, Acat, N);
    gemm_nt_kernel<false, false, 64, ushort_t><<<tM64 * 2, 256, 0, stream>>>(
        Acat, WsT + 2 * 128 * 256, bl[2], bl[4], 128, hbC, N, 256, tM64, 2);
    // a2+s2 aggregates fused: one gather pass over hbC -> Acat (a-half), AcatS (s-half)
    aggregate2_kernel<<<(N + 3) / 4, 256, 0, stream>>>(hbC, srcs, rowptr, deginv, Acat, AcatS, N);
    // a2: -> xh (fp32, direct to d_out)
    gemm_nt_kernel<false, false, 64, float><<<tM64, 256, 0, stream>>>(
        Acat, WsT + 4 * 128 * 256, bl[3], nullptr, BIG, xh_out, N, 128, tM64, 1);
    // s2: A = WTs2 (i over out-dim), B = AcatS (j over nodes), bias on i, C = s^T
    const int tM8 = (tM128 + 7) / 8;
    gemm_nt_kernel<true, true, 128, float><<<tM8 * tM8 * 64, 256, 0, stream>>>(
        WTs2, AcatS, bl[5], nullptr, BIG, outp, N, N, tM128, tM128);

    (void)n_in; (void)out_size; (void)ws_size;
}

// Round 4
// 652.200 us; speedup vs baseline: 1.2855x; 1.0332x over previous
//
#include <hip/hip_runtime.h>
#include <hip/hip_bf16.h>

typedef unsigned short ushort_t;
typedef unsigned int uint_t;
typedef __attribute__((ext_vector_type(8))) short short8;
typedef __attribute__((ext_vector_type(4))) float float4v;

__device__ __forceinline__ float bf2f(ushort_t u) {
    union { uint_t i; float f; } c; c.i = ((uint_t)u) << 16; return c.f;
}
__device__ __forceinline__ ushort_t f2bf(float f) {
    union { float f; uint_t i; } c; c.f = f;
    uint_t x = c.i;
    uint_t r = x + 0x7fffu + ((x >> 16) & 1u);   // RNE
    return (ushort_t)(r >> 16);
}

// async global->LDS, 16B per lane; LDS dest = wave-uniform base + lane*16
__device__ __forceinline__ void gl_lds16(const void* g, void* l) {
    __builtin_amdgcn_global_load_lds(
        (const __attribute__((address_space(1))) void*)g,
        (__attribute__((address_space(3))) void*)l, 16, 0, 0);
}

__device__ __forceinline__ void stv(float* p, float v) { *p = v; }
__device__ __forceinline__ void stv(ushort_t* p, float v) { *p = f2bf(v); }

// ---------------- graph setup: counting sort by dst ----------------
__global__ void hist_kernel(const int* __restrict__ dstv, int* __restrict__ cnt, int E) {
    int e = blockIdx.x * 256 + threadIdx.x;
    if (e < E) atomicAdd(&cnt[dstv[e]], 1);
}

// one block, 1024 threads: chunked scan (PER<=16 -> n<=16384)
__global__ __launch_bounds__(1024) void scan_kernel(
    const int* __restrict__ cnt, int* __restrict__ rowptr,
    int* __restrict__ cursor, float* __restrict__ deginv, int n) {
    __shared__ int sums[1024];
    const int t = threadIdx.x;
    const int per = (n + 1023) >> 10;
    const int b0 = t * per;
    int s = 0;
    for (int u = 0; u < per; u++) {
        int i = b0 + u;
        if (i < n) s += cnt[i];
    }
    sums[t] = s;
    __syncthreads();
    int x = s;
    for (int off = 1; off < 1024; off <<= 1) {
        int y = (t >= off) ? sums[t - off] : 0;
        __syncthreads();
        x += y;
        sums[t] = x;
        __syncthreads();
    }
    int run = x - s;   // exclusive prefix of this thread's chunk
    for (int u = 0; u < per; u++) {
        int i = b0 + u;
        if (i < n) {
            int v = cnt[i];
            rowptr[i] = run;
            cursor[i] = run;
            deginv[i] = 1.0f / (float)(v > 0 ? v : 1);
            run += v;
        }
    }
    if (t == 1023) rowptr[n] = x;
}

__global__ void scatter_kernel(const int* __restrict__ srcv, const int* __restrict__ dstv,
                               int* __restrict__ cursor, int* __restrict__ srcs_sorted, int E) {
    int e = blockIdx.x * 256 + threadIdx.x;
    if (e < E) {
        int p = atomicAdd(&cursor[dstv[e]], 1);
        srcs_sorted[p] = srcv[e];
    }
}

// ---------------- weight transpose ----------------
// Generic (for s2, Nout=N): WT[i][k] = bf16(Wcat[k][i]); Wcat=[W0;W1], WT [Nout][256].
__global__ __launch_bounds__(256) void transpose_w_kernel(
    const float* __restrict__ W0, const float* __restrict__ W1,
    ushort_t* __restrict__ WT, int Nout) {
    __shared__ ushort_t tile[64][72];
    const int i0 = blockIdx.x * 64;
    const int k0 = blockIdx.y * 64;
    const float* W = (k0 < 128) ? (W0 + (size_t)k0 * Nout)
                                : (W1 + (size_t)(k0 - 128) * Nout);
    const int tid = threadIdx.x;
    const int li = tid & 63;
    const int kq = tid >> 6;
    const int gi = i0 + li;
    const bool ok = gi < Nout;
    for (int k = kq; k < 64; k += 4) {
        float v = ok ? W[(size_t)k * Nout + gi] : 0.f;
        tile[li][k] = f2bf(v);
    }
    __syncthreads();
    for (int s = tid; s < 512; s += 256) {
        int r = s >> 3, ch = s & 7;
        int gi2 = i0 + r;
        if (gi2 < Nout)
            *(short8*)(WT + (size_t)gi2 * 256 + k0 + ch * 8) = *(const short8*)&tile[r][ch * 8];
    }
}

// Batched transpose for the 5 square (Nout=128) layers in ONE launch.
struct W5 { const float* W0[5]; const float* W1[5]; };
__global__ __launch_bounds__(256) void transpose_w5_kernel(W5 wp, ushort_t* __restrict__ WT) {
    __shared__ ushort_t tile[64][72];
    const int layer = blockIdx.z;
    const int i0 = blockIdx.x * 64;            // 0 or 64
    const int k0 = blockIdx.y * 64;            // 0,64,128,192
    const float* W = (k0 < 128) ? (wp.W0[layer] + (size_t)k0 * 128)
                                : (wp.W1[layer] + (size_t)(k0 - 128) * 128);
    ushort_t* WTb = WT + (size_t)layer * 128 * 256;
    const int tid = threadIdx.x;
    const int li = tid & 63;
    const int kq = tid >> 6;
    const int gi = i0 + li;
    for (int k = kq; k < 64; k += 4)
        tile[li][k] = f2bf(W[(size_t)k * 128 + gi]);
    __syncthreads();
    for (int s = tid; s < 512; s += 256) {
        int r = s >> 3, ch = s & 7;
        *(short8*)(WTb + (size_t)(i0 + r) * 256 + k0 + ch * 8) = *(const short8*)&tile[r][ch * 8];
    }
}

// ---------------- aggregation (wave per node) ----------------
// Acat[n][0:128] = bf16(mean of act[src]); Acat[n][128:256] = bf16(act[n])
template <typename TIN>
__device__ __forceinline__ float2 ld2(const TIN* act, size_t row, int t);
template <>
__device__ __forceinline__ float2 ld2<float>(const float* act, size_t row, int t) {
    return ((const float2*)act)[row * 64 + t];
}
template <>
__device__ __forceinline__ float2 ld2<ushort_t>(const ushort_t* act, size_t row, int t) {
    uint_t u = ((const uint_t*)act)[row * 64 + t];
    float2 r; r.x = bf2f((ushort_t)(u & 0xffffu)); r.y = bf2f((ushort_t)(u >> 16));
    return r;
}

template <typename TIN>
__global__ __launch_bounds__(256) void aggregate_kernel(
    const TIN* __restrict__ act, const int* __restrict__ srcs,
    const int* __restrict__ rowptr, const float* __restrict__ deginv,
    ushort_t* __restrict__ Acat, int N) {
    int node = blockIdx.x * 4 + (threadIdx.x >> 6);
    if (node >= N) return;
    int t = threadIdx.x & 63;
    int e0 = rowptr[node], e1 = rowptr[node + 1];
    float ax = 0.f, ay = 0.f;
    int e = e0;
    for (; e + 4 <= e1; e += 4) {
        int s0 = srcs[e], s1 = srcs[e + 1], s2 = srcs[e + 2], s3 = srcs[e + 3];
        float2 v0 = ld2(act, (size_t)s0, t);
        float2 v1 = ld2(act, (size_t)s1, t);
        float2 v2 = ld2(act, (size_t)s2, t);
        float2 v3 = ld2(act, (size_t)s3, t);
        ax += v0.x + v1.x + v2.x + v3.x;
        ay += v0.y + v1.y + v2.y + v3.y;
    }
    for (; e < e1; e++) {
        float2 v = ld2(act, (size_t)srcs[e], t);
        ax += v.x; ay += v.y;
    }
    float dinv = deginv[node];
    uint_t m = ((uint_t)f2bf(ay * dinv) << 16) | (uint_t)f2bf(ax * dinv);
    float2 self = ld2(act, (size_t)node, t);
    uint_t sf = ((uint_t)f2bf(self.y) << 16) | (uint_t)f2bf(self.x);
    ((uint_t*)Acat)[(size_t)node * 128 + t]      = m;
    ((uint_t*)Acat)[(size_t)node * 128 + 64 + t] = sf;
}

// Fused aggregate over a [N][256] bf16 activation (a-half cols 0:128, s-half 128:256):
// ONE gather pass produces AcatA (from a-half) and AcatS (from s-half).
__global__ __launch_bounds__(256) void aggregate2_kernel(
    const ushort_t* __restrict__ act, const int* __restrict__ srcs,
    const int* __restrict__ rowptr, const float* __restrict__ deginv,
    ushort_t* __restrict__ AcatA, ushort_t* __restrict__ AcatS, int N) {
    int node = blockIdx.x * 4 + (threadIdx.x >> 6);
    if (node >= N) return;
    int t = threadIdx.x & 63;
    const uint_t* A = (const uint_t*)act;
    int e0 = rowptr[node], e1 = rowptr[node + 1];
    float ax = 0.f, ay = 0.f, sx = 0.f, sy = 0.f;
    int e = e0;
    for (; e + 4 <= e1; e += 4) {
        size_t r0 = (size_t)srcs[e] * 128,     r1 = (size_t)srcs[e + 1] * 128;
        size_t r2 = (size_t)srcs[e + 2] * 128, r3 = (size_t)srcs[e + 3] * 128;
        uint_t ua0 = A[r0 + t], us0 = A[r0 + 64 + t];
        uint_t ua1 = A[r1 + t], us1 = A[r1 + 64 + t];
        uint_t ua2 = A[r2 + t], us2 = A[r2 + 64 + t];
        uint_t ua3 = A[r3 + t], us3 = A[r3 + 64 + t];
        ax += bf2f((ushort_t)(ua0 & 0xffffu)) + bf2f((ushort_t)(ua1 & 0xffffu))
            + bf2f((ushort_t)(ua2 & 0xffffu)) + bf2f((ushort_t)(ua3 & 0xffffu));
        ay += bf2f((ushort_t)(ua0 >> 16))     + bf2f((ushort_t)(ua1 >> 16))
            + bf2f((ushort_t)(ua2 >> 16))     + bf2f((ushort_t)(ua3 >> 16));
        sx += bf2f((ushort_t)(us0 & 0xffffu)) + bf2f((ushort_t)(us1 & 0xffffu))
            + bf2f((ushort_t)(us2 & 0xffffu)) + bf2f((ushort_t)(us3 & 0xffffu));
        sy += bf2f((ushort_t)(us0 >> 16))     + bf2f((ushort_t)(us1 >> 16))
            + bf2f((ushort_t)(us2 >> 16))     + bf2f((ushort_t)(us3 >> 16));
    }
    for (; e < e1; e++) {
        size_t r0 = (size_t)srcs[e] * 128;
        uint_t ua0 = A[r0 + t], us0 = A[r0 + 64 + t];
        ax += bf2f((ushort_t)(ua0 & 0xffffu));
        ay += bf2f((ushort_t)(ua0 >> 16));
        sx += bf2f((ushort_t)(us0 & 0xffffu));
        sy += bf2f((ushort_t)(us0 >> 16));
    }
    float dinv = deginv[node];
    size_t rb = (size_t)node * 128;
    uint_t sa = A[rb + t], ss = A[rb + 64 + t];   // self rows already bf16
    ((uint_t*)AcatA)[rb + t]      = ((uint_t)f2bf(ay * dinv) << 16) | (uint_t)f2bf(ax * dinv);
    ((uint_t*)AcatA)[rb + 64 + t] = sa;
    ((uint_t*)AcatS)[rb + t]      = ((uint_t)f2bf(sy * dinv) << 16) | (uint_t)f2bf(sx * dinv);
    ((uint_t*)AcatS)[rb + 64 + t] = ss;
}

// ---------------- NT GEMM: C[i][j] = relu(sum_k A[i][k]*B[j][k] + bias) ----------------
// A:[rowsA][256] bf16, B:[rowsB][256] bf16, C:[rowsA][rowsB] (ldc=rowsB).
// bias indexed by i (BIAS_I) or j (with optional second vector bias2 for j>=jsplit).
// TM in {128, 64}: output tile TM x 128, 4 waves (2x2), wave tile (TM/2) x 64.
// K-loop: 2-phase pipeline, double-buffered LDS, counted vmcnt. Barrier discipline
// (race-fixed vs R3): vmcnt(NLD) -> s_barrier -> mem-fence -> ds_read+MFMA ->
// s_waitcnt lgkmcnt(0) (DS-queue drain: ISA §8 "s_waitcnt first if data dep") +
// sched_barrier(0) -> s_barrier -> mem-fence.
// SWZ: 2-D 8x8 supergroups + bijective XCD chunking; grid must be tM8*tN8*64.
// Non-SWZ: exact grid tilesM*tilesN, GRP=8 M-grouping.
// fp32 output: LDS-transposed epilogue, nontemporal dwordx4 stores (write-once stream).
template <bool BIAS_I, bool SWZ, int TM, typename TOUT>
__global__ __launch_bounds__(256) void gemm_nt_kernel(
    const ushort_t* __restrict__ A, const ushort_t* __restrict__ B,
    const float* __restrict__ bias, const float* __restrict__ bias2, int jsplit,
    TOUT* __restrict__ C, int rowsA, int rowsB, int tilesM, int tilesN) {
    constexpr int IMN = TM / 32;               // A-fragments per wave (4 or 2)
    constexpr int NLD = IMN + 4;               // VMEM insts per stage per wave
    constexpr int ABYTES = TM * 128;           // A tile: TM x 64 bf16
    constexpr int BBYTES = 128 * 128;          // B tile: 128 x 64 bf16
    __shared__ __align__(16) char smem[2 * (ABYTES + BBYTES)];

    int pid_m, pid_n;
    if (SWZ) {
        const int lin = blockIdx.x;
        const int nwg = gridDim.x;                 // multiple of 64 -> %8==0
        const int w = (lin & 7) * (nwg >> 3) + (lin >> 3);   // XCD chunk (bijective)
        const int tM8 = (tilesM + 7) >> 3;
        const int sg = w >> 6, is = w & 63;        // 8x8 supergroup
        const int sgm = sg % tM8, sgn = sg / tM8;
        pid_m = sgm * 8 + (is & 7);
        pid_n = sgn * 8 + (is >> 3);
        if (pid_m >= tilesM || pid_n >= tilesN) return;   // block-uniform exit
    } else {
        const int lin = blockIdx.x;
        const int GRP = 8;
        const int nig = GRP * tilesN;
        const int gidg = lin / nig;
        const int first_m = gidg * GRP;
        const int gsz = min(tilesM - first_m, GRP);
        const int in_grp = lin - gidg * nig;
        pid_m = first_m + (in_grp % gsz);
        pid_n = in_grp / gsz;
    }
    const int i0 = pid_m * TM;
    const int j0 = pid_n * 128;

    const int tid  = threadIdx.x;
    const int lane = tid & 63;
    const int wid  = tid >> 6;
    const int wm = wid >> 1, wn = wid & 1;
    const int r16 = lane & 15, quad = lane >> 4;
    const int rsub = lane >> 3;              // row-in-window 0..7
    const int csw  = (lane & 7) ^ rsub;      // swizzled global chunk for staging

    float4v acc[IMN][4];
#pragma unroll
    for (int a = 0; a < IMN; a++)
#pragma unroll
        for (int b = 0; b < 4; b++) acc[a][b] = (float4v){0.f, 0.f, 0.f, 0.f};

    // stage K-tile kt into buffer buf (NLD VMEM insts per wave)
    auto stage = [&](int buf, int kt) {
        ushort_t* Ad = (ushort_t*)(smem + buf * (ABYTES + BBYTES));
        ushort_t* Bd = (ushort_t*)(smem + buf * (ABYTES + BBYTES) + ABYTES);
        const int kbase = kt * 64 + csw * 8;
#pragma unroll
        for (int t = 0; t < IMN; t++) {          // A: TM rows = IMN windows/wave
            const int w8 = (wid * IMN + t) * 8;
            int rA = min(i0 + w8 + rsub, rowsA - 1);
            gl_lds16(A + (size_t)rA * 256 + kbase, Ad + w8 * 64);
        }
#pragma unroll
        for (int t = 0; t < 4; t++) {            // B: 128 rows = 4 windows/wave
            const int w8 = (wid * 4 + t) * 8;
            int rB = min(j0 + w8 + rsub, rowsB - 1);
            gl_lds16(B + (size_t)rB * 256 + kbase, Bd + w8 * 64);
        }
    };

    stage(0, 0);                                 // prologue
#pragma unroll
    for (int kt = 0; kt < 4; kt++) {
        if (kt < 3) {
            stage((kt + 1) & 1, kt + 1);         // prefetch next tile (other buffer)
            asm volatile("s_waitcnt vmcnt(%0)" :: "n"(NLD) : "memory");  // cur landed
        } else {
            asm volatile("s_waitcnt vmcnt(0)" ::: "memory");
        }
        __builtin_amdgcn_s_barrier();            // all waves: cur tile fully in LDS
        asm volatile("" ::: "memory");           // fence: no ds_read hoists above barrier
        const ushort_t* Ac = (const ushort_t*)(smem + (kt & 1) * (ABYTES + BBYTES));
        const ushort_t* Bc = Ac + ABYTES / 2;    // ushort elements offset = ABYTES bytes
#pragma unroll
        for (int ks = 0; ks < 2; ks++) {
            const int chb = ks * 4 + quad;
            const int sw = ((chb ^ (r16 & 7))) * 8;
            short8 af[IMN], bfr[4];
#pragma unroll
            for (int im = 0; im < IMN; im++)
                af[im] = *(const short8*)(Ac + (wm * (TM / 2) + im * 16 + r16) * 64 + sw);
#pragma unroll
            for (int jn = 0; jn < 4; jn++)
                bfr[jn] = *(const short8*)(Bc + (wn * 64 + jn * 16 + r16) * 64 + sw);
#pragma unroll
            for (int im = 0; im < IMN; im++)
#pragma unroll
                for (int jn = 0; jn < 4; jn++)
                    acc[im][jn] = __builtin_amdgcn_mfma_f32_16x16x32_bf16(
                        af[im], bfr[jn], acc[im][jn], 0, 0, 0);
        }
        if (kt < 3) {
            // DS queue must be drained before any wave re-stages this buffer (HW race
            // otherwise: queued ds_read can execute after another wave's LDS write).
            asm volatile("s_waitcnt lgkmcnt(0)" ::: "memory");
            __builtin_amdgcn_sched_barrier(0);
            __builtin_amdgcn_s_barrier();        // reads of cur done -> re-stageable
            asm volatile("" ::: "memory");       // no load_lds hoists above barrier
        }
    }

    const int rows_lim = rowsA - i0;
    const int cols_lim = rowsB - j0;

    if constexpr (sizeof(TOUT) == 4) {
        // ---- fp32: LDS-transposed epilogue, 32-row chunks, pitch 132 (2-way=free) ----
        float* T = (float*)smem;                 // 32*132*4 = 16896 B <= stage area
        constexpr int NCH = TM / 32;
#pragma unroll
        for (int c = 0; c < NCH; c++) {
            const int crow = c * 32;
            __syncthreads();                     // full drain: LDS free for reuse
            if (wm == crow / (TM / 2)) {
                const int imb = (crow - wm * (TM / 2)) / 16;
#pragma unroll
                for (int ii = 0; ii < 2; ii++) {
                    const int im = imb + ii;
#pragma unroll
                    for (int jn = 0; jn < 4; jn++) {
                        const int jl = wn * 64 + jn * 16 + r16;
                        float bj = 0.f;
                        if (!BIAS_I) {
                            int jg = j0 + jl;
                            bj = (jg >= jsplit) ? bias2[jg - jsplit] : bias[jg];
                        }
#pragma unroll
                        for (int r = 0; r < 4; r++) {
                            const int rl = ii * 16 + quad * 4 + r;
                            float bv = BIAS_I ? bias[min(i0 + crow + rl, rowsA - 1)] : bj;
                            T[rl * 132 + jl] = fmaxf(acc[im][jn][r] + bv, 0.f);
                        }
                    }
                }
            }
            __syncthreads();
            const int c4 = tid & 31, rl0 = tid >> 5;
#pragma unroll
            for (int s = 0; s < 4; s++) {
                const int rl = rl0 + s * 8;
                const int il = crow + rl;
                if (il < rows_lim) {
                    const int jl = c4 * 4;
                    float* dst = (float*)C + (size_t)(i0 + il) * rowsB + j0 + jl;
                    if (jl + 4 <= cols_lim) {
                        float4v vv = *(const float4v*)&T[rl * 132 + jl];
                        __builtin_nontemporal_store(vv, (float4v*)dst);
                    } else {
                        for (int jj = 0; jj < 4; jj++)
                            if (jl + jj < cols_lim) dst[jj] = T[rl * 132 + jl + jj];
                    }
                }
            }
        }
    } else {
        // ---- bf16: direct scalar stores (small outputs, re-read next layer) ----
#pragma unroll
        for (int im = 0; im < IMN; im++) {
#pragma unroll
            for (int jn = 0; jn < 4; jn++) {
                const int jl = wn * 64 + jn * 16 + r16;
                if (jl < cols_lim) {
                    float bj = 0.f;
                    if (!BIAS_I) {
                        int jg = j0 + jl;
                        bj = (jg >= jsplit) ? bias2[jg - jsplit] : bias[jg];
                    }
#pragma unroll
                    for (int r = 0; r < 4; r++) {
                        const int il = wm * (TM / 2) + im * 16 + quad * 4 + r;
                        if (il < rows_lim) {
                            float bv = BIAS_I ? bias[i0 + il] : bj;
                            float v = fmaxf(acc[im][jn][r] + bv, 0.f);
                            stv(C + (size_t)(i0 + il) * rowsB + (j0 + jl), v);
                        }
                    }
                }
            }
        }
    }
}

// ---------------- host launch ----------------
extern "C" void kernel_launch(void* const* d_in, const int* in_sizes, int n_in,
                              void* d_out, int out_size, void* d_ws, size_t ws_size,
                              hipStream_t stream) {
    const int N = in_sizes[18];       // bl_s2 length == num nodes
    const int E = in_sizes[1] / 2;

    const float* x = (const float*)d_in[0];
    const int* ei = (const int*)d_in[1];
    const int* srcv = ei;
    const int* dstv = ei + E;

    // layer order in inputs: e1, e2, a1, a2, s1, s2
    const float* Wl[6] = {(const float*)d_in[2],  (const float*)d_in[5],
                          (const float*)d_in[8],  (const float*)d_in[11],
                          (const float*)d_in[14], (const float*)d_in[17]};
    const float* bl[6] = {(const float*)d_in[3],  (const float*)d_in[6],
                          (const float*)d_in[9],  (const float*)d_in[12],
                          (const float*)d_in[15], (const float*)d_in[18]};
    const float* Wr[6] = {(const float*)d_in[4],  (const float*)d_in[7],
                          (const float*)d_in[10], (const float*)d_in[13],
                          (const float*)d_in[16], (const float*)d_in[19]};

    char* p = (char*)d_ws;
    auto carve = [&](size_t bytes) -> char* {
        char* q = p;
        p += (bytes + 255) & ~(size_t)255;
        return q;
    };
    int*      cnt    = (int*)carve((size_t)N * 4);
    int*      rowptr = (int*)carve((size_t)(N + 1) * 4);
    int*      cursor = (int*)carve((size_t)N * 4);
    float*    deginv = (float*)carve((size_t)N * 4);
    int*      srcs   = (int*)carve((size_t)E * 4);
    ushort_t* Acat   = (ushort_t*)carve((size_t)N * 256 * 2);
    ushort_t* AcatS  = (ushort_t*)carve((size_t)N * 256 * 2);
    ushort_t* hbA    = (ushort_t*)carve((size_t)N * 128 * 2);   // bf16 activations
    ushort_t* hbB    = (ushort_t*)carve((size_t)N * 128 * 2);
    ushort_t* hbC    = (ushort_t*)carve((size_t)N * 256 * 2);   // a1|s1 fused output
    ushort_t* WTs2   = (ushort_t*)carve((size_t)N * 256 * 2);   // s2 weights transposed
    ushort_t* WsT    = (ushort_t*)carve((size_t)5 * 128 * 256 * 2);

    hipMemsetAsync(cnt, 0, (size_t)N * 4, stream);
    hist_kernel<<<(E + 255) / 256, 256, 0, stream>>>(dstv, cnt, E);
    scan_kernel<<<1, 1024, 0, stream>>>(cnt, rowptr, cursor, deginv, N);
    scatter_kernel<<<(E + 255) / 256, 256, 0, stream>>>(srcv, dstv, cursor, srcs, E);

    // transpose the 5 square layers in WsT order [e1, e2, a1, s1, a2]
    // (a1 and s1 contiguous -> their GEMMs fuse into one 256-col GEMM)
    W5 w5;
    w5.W0[0] = Wl[0]; w5.W1[0] = Wr[0];   // e1
    w5.W0[1] = Wl[1]; w5.W1[1] = Wr[1];   // e2
    w5.W0[2] = Wl[2]; w5.W1[2] = Wr[2];   // a1
    w5.W0[3] = Wl[4]; w5.W1[3] = Wr[4];   // s1
    w5.W0[4] = Wl[3]; w5.W1[4] = Wr[3];   // a2
    transpose_w5_kernel<<<dim3(2, 4, 5), 256, 0, stream>>>(w5, WsT);
    transpose_w_kernel<<<dim3((N + 63) / 64, 4), 256, 0, stream>>>(
        Wl[5], Wr[5], WTs2, N);

    float* outp = (float*)d_out;
    float* xh_out = outp + (size_t)N * N;

    const int tM128 = (N + 127) / 128;    // 79  (s2 tiles)
    const int tM64  = (N + 63) / 64;      // 157 (small-GEMM tiles)
    const int BIG = 1 << 30;

    // e1: x(fp32) -> hbA
    aggregate_kernel<float><<<(N + 3) / 4, 256, 0, stream>>>(x, srcs, rowptr, deginv, Acat, N);
    gemm_nt_kernel<false, false, 64, ushort_t><<<tM64, 256, 0, stream>>>(
        Acat, WsT + 0 * 128 * 256, bl[0], nullptr, BIG, hbA, N, 128, tM64, 1);
    // e2: hbA -> hbB (h)
    aggregate_kernel<ushort_t><<<(N + 3) / 4, 256, 0, stream>>>(hbA, srcs, rowptr, deginv, Acat, N);
    gemm_nt_kernel<false, false, 64, ushort_t><<<tM64, 256, 0, stream>>>(
        Acat, WsT + 1 * 128 * 256, bl[1], nullptr, BIG, hbB, N, 128, tM64, 1);
    // a1+s1 fused: ONE aggregate of h, ONE GEMM with 256 output cols -> hbC
    aggregate_kernel<ushort_t><<<(N + 3) / 4, 256, 0, stream>>>(hbB, srcs, rowptr, deginv, Acat, N);
    gemm_nt_kernel<false, false, 64, ushort_t><<<tM64 * 2, 256, 0, stream>>>(
        Acat, WsT + 2 * 128 * 256, bl[2], bl[4], 128, hbC, N, 256, tM64, 2);
    // a2+s2 aggregates fused: one gather pass over hbC -> Acat (a-half), AcatS (s-half)
    aggregate2_kernel<<<(N + 3) / 4, 256, 0, stream>>>(hbC, srcs, rowptr, deginv, Acat, AcatS, N);
    // a2: -> xh (fp32, direct to d_out)
    gemm_nt_kernel<false, false, 64, float><<<tM64, 256, 0, stream>>>(
        Acat, WsT + 4 * 128 * 256, bl[3], nullptr, BIG, xh_out, N, 128, tM64, 1);
    // s2: A = WTs2 (i over out-dim), B = AcatS (j over nodes), bias on i, C = s^T
    const int tM8 = (tM128 + 7) / 8;
    gemm_nt_kernel<true, true, 128, float><<<tM8 * tM8 * 64, 256, 0, stream>>>(
        WTs2, AcatS, bl[5], nullptr, BIG, outp, N, N, tM128, tM128);

    (void)n_in; (void)out_size; (void)ws_size;
}

// Round 6
// 640.700 us; speedup vs baseline: 1.3085x; 1.0179x over previous
//
#include <hip/hip_runtime.h>
#include <hip/hip_bf16.h>

typedef unsigned short ushort_t;
typedef unsigned int uint_t;
typedef __attribute__((ext_vector_type(8))) short short8;
typedef __attribute__((ext_vector_type(4))) float float4v;

__device__ __forceinline__ float bf2f(ushort_t u) {
    union { uint_t i; float f; } c; c.i = ((uint_t)u) << 16; return c.f;
}
__device__ __forceinline__ ushort_t f2bf(float f) {
    union { float f; uint_t i; } c; c.f = f;
    uint_t x = c.i;
    uint_t r = x + 0x7fffu + ((x >> 16) & 1u);   // RNE
    return (ushort_t)(r >> 16);
}

// async global->LDS, 16B per lane; LDS dest = wave-uniform base + lane*16
__device__ __forceinline__ void gl_lds16(const void* g, void* l) {
    __builtin_amdgcn_global_load_lds(
        (const __attribute__((address_space(1))) void*)g,
        (__attribute__((address_space(3))) void*)l, 16, 0, 0);
}

__device__ __forceinline__ void stv(float* p, float v) { *p = v; }
__device__ __forceinline__ void stv(ushort_t* p, float v) { *p = f2bf(v); }

// ---------------- graph setup: counting sort by dst ----------------
// one block, 1024 threads: chunked scan (PER<=16 -> n<=16384)
__global__ __launch_bounds__(1024) void scan_kernel(
    const int* __restrict__ cnt, int* __restrict__ rowptr,
    int* __restrict__ cursor, float* __restrict__ deginv, int n) {
    __shared__ int sums[1024];
    const int t = threadIdx.x;
    const int per = (n + 1023) >> 10;
    const int b0 = t * per;
    int s = 0;
    for (int u = 0; u < per; u++) {
        int i = b0 + u;
        if (i < n) s += cnt[i];
    }
    sums[t] = s;
    __syncthreads();
    int x = s;
    for (int off = 1; off < 1024; off <<= 1) {
        int y = (t >= off) ? sums[t - off] : 0;
        __syncthreads();
        x += y;
        sums[t] = x;
        __syncthreads();
    }
    int run = x - s;   // exclusive prefix of this thread's chunk
    for (int u = 0; u < per; u++) {
        int i = b0 + u;
        if (i < n) {
            int v = cnt[i];
            rowptr[i] = run;
            cursor[i] = run;
            deginv[i] = 1.0f / (float)(v > 0 ? v : 1);
            run += v;
        }
    }
    if (t == 1023) rowptr[n] = x;
}

__global__ void scatter_kernel(const int* __restrict__ srcv, const int* __restrict__ dstv,
                               int* __restrict__ cursor, int* __restrict__ srcs_sorted, int E) {
    int e = blockIdx.x * 256 + threadIdx.x;
    if (e < E) {
        int p = atomicAdd(&cursor[dstv[e]], 1);
        srcs_sorted[p] = srcv[e];
    }
}

// ---------------- fused setup: w5 transposes + ws2 transpose + hist ----------------
// blocks [0,40): square-layer transpose tiles (5 layers x 2 x 4)
// blocks [40, 40+nbx*4): s2 transpose tiles
// blocks [40+nbx*4, ...): histogram over edges
struct W5 { const float* W0[5]; const float* W1[5]; };

__global__ __launch_bounds__(256) void setup_kernel(
    W5 wp, ushort_t* __restrict__ WT,
    const float* __restrict__ Ws2_0, const float* __restrict__ Ws2_1,
    ushort_t* __restrict__ WTs2, int Nout, int nbx,
    const int* __restrict__ dstv, int* __restrict__ cnt, int E) {
    __shared__ ushort_t tile[64][72];
    const int b = blockIdx.x;
    const int tid = threadIdx.x;
    if (b < 40) {
        // square layer (128x128) tile: WT[i][k] = bf16(W[k][i])
        const int bx = b & 1, by = (b >> 1) & 3, layer = b >> 3;
        const int i0 = bx * 64, k0 = by * 64;
        const float* W = (k0 < 128) ? (wp.W0[layer] + (size_t)k0 * 128)
                                    : (wp.W1[layer] + (size_t)(k0 - 128) * 128);
        ushort_t* WTb = WT + (size_t)layer * 128 * 256;
        const int li = tid & 63;
        const int kq = tid >> 6;
        const int gi = i0 + li;
        for (int k = kq; k < 64; k += 4)
            tile[li][k] = f2bf(W[(size_t)k * 128 + gi]);
        __syncthreads();
        for (int s = tid; s < 512; s += 256) {
            int r = s >> 3, ch = s & 7;
            *(short8*)(WTb + (size_t)(i0 + r) * 256 + k0 + ch * 8) = *(const short8*)&tile[r][ch * 8];
        }
    } else if (b < 40 + nbx * 4) {
        // s2 (Nout x 256) tile with tail guards
        const int vt = b - 40;
        const int bx = vt % nbx, by = vt / nbx;
        const int i0 = bx * 64, k0 = by * 64;
        const float* W = (k0 < 128) ? (Ws2_0 + (size_t)k0 * Nout)
                                    : (Ws2_1 + (size_t)(k0 - 128) * Nout);
        const int li = tid & 63;
        const int kq = tid >> 6;
        const int gi = i0 + li;
        const bool ok = gi < Nout;
        for (int k = kq; k < 64; k += 4) {
            float v = ok ? W[(size_t)k * Nout + gi] : 0.f;
            tile[li][k] = f2bf(v);
        }
        __syncthreads();
        for (int s = tid; s < 512; s += 256) {
            int r = s >> 3, ch = s & 7;
            int gi2 = i0 + r;
            if (gi2 < Nout)
                *(short8*)(WTs2 + (size_t)gi2 * 256 + k0 + ch * 8) = *(const short8*)&tile[r][ch * 8];
        }
    } else {
        // histogram
        int e = (b - 40 - nbx * 4) * 256 + tid;
        if (e < E) atomicAdd(&cnt[dstv[e]], 1);
    }
}

// ---------------- aggregation (wave per node) ----------------
// Acat[n][0:128] = bf16(mean of act[src]); Acat[n][128:256] = bf16(act[n])
template <typename TIN>
__device__ __forceinline__ float2 ld2(const TIN* act, size_t row, int t);
template <>
__device__ __forceinline__ float2 ld2<float>(const float* act, size_t row, int t) {
    return ((const float2*)act)[row * 64 + t];
}
template <>
__device__ __forceinline__ float2 ld2<ushort_t>(const ushort_t* act, size_t row, int t) {
    uint_t u = ((const uint_t*)act)[row * 64 + t];
    float2 r; r.x = bf2f((ushort_t)(u & 0xffffu)); r.y = bf2f((ushort_t)(u >> 16));
    return r;
}

template <typename TIN>
__global__ __launch_bounds__(256) void aggregate_kernel(
    const TIN* __restrict__ act, const int* __restrict__ srcs,
    const int* __restrict__ rowptr, const float* __restrict__ deginv,
    ushort_t* __restrict__ Acat, int N) {
    int node = blockIdx.x * 4 + (threadIdx.x >> 6);
    if (node >= N) return;
    int t = threadIdx.x & 63;
    int e0 = rowptr[node], e1 = rowptr[node + 1];
    float ax = 0.f, ay = 0.f;
    int e = e0;
    for (; e + 4 <= e1; e += 4) {
        int s0 = srcs[e], s1 = srcs[e + 1], s2 = srcs[e + 2], s3 = srcs[e + 3];
        float2 v0 = ld2(act, (size_t)s0, t);
        float2 v1 = ld2(act, (size_t)s1, t);
        float2 v2 = ld2(act, (size_t)s2, t);
        float2 v3 = ld2(act, (size_t)s3, t);
        ax += v0.x + v1.x + v2.x + v3.x;
        ay += v0.y + v1.y + v2.y + v3.y;
    }
    for (; e < e1; e++) {
        float2 v = ld2(act, (size_t)srcs[e], t);
        ax += v.x; ay += v.y;
    }
    float dinv = deginv[node];
    uint_t m = ((uint_t)f2bf(ay * dinv) << 16) | (uint_t)f2bf(ax * dinv);
    float2 self = ld2(act, (size_t)node, t);
    uint_t sf = ((uint_t)f2bf(self.y) << 16) | (uint_t)f2bf(self.x);
    ((uint_t*)Acat)[(size_t)node * 128 + t]      = m;
    ((uint_t*)Acat)[(size_t)node * 128 + 64 + t] = sf;
}

// Fused aggregate over a [N][256] bf16 activation (a-half cols 0:128, s-half 128:256):
// ONE gather pass produces AcatA (from a-half) and AcatS (from s-half).
__global__ __launch_bounds__(256) void aggregate2_kernel(
    const ushort_t* __restrict__ act, const int* __restrict__ srcs,
    const int* __restrict__ rowptr, const float* __restrict__ deginv,
    ushort_t* __restrict__ AcatA, ushort_t* __restrict__ AcatS, int N) {
    int node = blockIdx.x * 4 + (threadIdx.x >> 6);
    if (node >= N) return;
    int t = threadIdx.x & 63;
    const uint_t* A = (const uint_t*)act;
    int e0 = rowptr[node], e1 = rowptr[node + 1];
    float ax = 0.f, ay = 0.f, sx = 0.f, sy = 0.f;
    int e = e0;
    for (; e + 4 <= e1; e += 4) {
        size_t r0 = (size_t)srcs[e] * 128,     r1 = (size_t)srcs[e + 1] * 128;
        size_t r2 = (size_t)srcs[e + 2] * 128, r3 = (size_t)srcs[e + 3] * 128;
        uint_t ua0 = A[r0 + t], us0 = A[r0 + 64 + t];
        uint_t ua1 = A[r1 + t], us1 = A[r1 + 64 + t];
        uint_t ua2 = A[r2 + t], us2 = A[r2 + 64 + t];
        uint_t ua3 = A[r3 + t], us3 = A[r3 + 64 + t];
        ax += bf2f((ushort_t)(ua0 & 0xffffu)) + bf2f((ushort_t)(ua1 & 0xffffu))
            + bf2f((ushort_t)(ua2 & 0xffffu)) + bf2f((ushort_t)(ua3 & 0xffffu));
        ay += bf2f((ushort_t)(ua0 >> 16))     + bf2f((ushort_t)(ua1 >> 16))
            + bf2f((ushort_t)(ua2 >> 16))     + bf2f((ushort_t)(ua3 >> 16));
        sx += bf2f((ushort_t)(us0 & 0xffffu)) + bf2f((ushort_t)(us1 & 0xffffu))
            + bf2f((ushort_t)(us2 & 0xffffu)) + bf2f((ushort_t)(us3 & 0xffffu));
        sy += bf2f((ushort_t)(us0 >> 16))     + bf2f((ushort_t)(us1 >> 16))
            + bf2f((ushort_t)(us2 >> 16))     + bf2f((ushort_t)(us3 >> 16));
    }
    for (; e < e1; e++) {
        size_t r0 = (size_t)srcs[e] * 128;
        uint_t ua0 = A[r0 + t], us0 = A[r0 + 64 + t];
        ax += bf2f((ushort_t)(ua0 & 0xffffu));
        ay += bf2f((ushort_t)(ua0 >> 16));
        sx += bf2f((ushort_t)(us0 & 0xffffu));
        sy += bf2f((ushort_t)(us0 >> 16));
    }
    float dinv = deginv[node];
    size_t rb = (size_t)node * 128;
    uint_t sa = A[rb + t], ss = A[rb + 64 + t];   // self rows already bf16
    ((uint_t*)AcatA)[rb + t]      = ((uint_t)f2bf(ay * dinv) << 16) | (uint_t)f2bf(ax * dinv);
    ((uint_t*)AcatA)[rb + 64 + t] = sa;
    ((uint_t*)AcatS)[rb + t]      = ((uint_t)f2bf(sy * dinv) << 16) | (uint_t)f2bf(sx * dinv);
    ((uint_t*)AcatS)[rb + 64 + t] = ss;
}

// ---------------- NT GEMM tile body (R4-proven) ----------------
// C[i][j] = relu(sum_k A[i][k]*B[j][k] + bias); A:[rowsA][256], B:[rowsB][256] bf16.
// 2-phase double-buffered pipeline, counted vmcnt, race-fixed barrier discipline:
// vmcnt(NLD) -> s_barrier -> fence -> ds_read+MFMA -> lgkmcnt(0)+sched_barrier ->
// s_barrier -> fence. fp32 epilogue: LDS-transposed, nontemporal dwordx4 stores.
template <bool BIAS_I, int TM, typename TOUT>
__device__ __forceinline__ void gemm_tile_body(
    char* smem, int pid_m, int pid_n,
    const ushort_t* __restrict__ A, const ushort_t* __restrict__ B,
    const float* __restrict__ bias, const float* __restrict__ bias2, int jsplit,
    TOUT* __restrict__ C, int rowsA, int rowsB) {
    constexpr int IMN = TM / 32;               // A-fragments per wave (4 or 2)
    constexpr int NLD = IMN + 4;               // VMEM insts per stage per wave
    constexpr int ABYTES = TM * 128;           // A tile: TM x 64 bf16
    constexpr int BBYTES = 128 * 128;          // B tile: 128 x 64 bf16

    const int i0 = pid_m * TM;
    const int j0 = pid_n * 128;

    const int tid  = threadIdx.x;
    const int lane = tid & 63;
    const int wid  = tid >> 6;
    const int wm = wid >> 1, wn = wid & 1;
    const int r16 = lane & 15, quad = lane >> 4;
    const int rsub = lane >> 3;              // row-in-window 0..7
    const int csw  = (lane & 7) ^ rsub;      // swizzled global chunk for staging

    float4v acc[IMN][4];
#pragma unroll
    for (int a = 0; a < IMN; a++)
#pragma unroll
        for (int b = 0; b < 4; b++) acc[a][b] = (float4v){0.f, 0.f, 0.f, 0.f};

    auto stage = [&](int buf, int kt) {
        ushort_t* Ad = (ushort_t*)(smem + buf * (ABYTES + BBYTES));
        ushort_t* Bd = (ushort_t*)(smem + buf * (ABYTES + BBYTES) + ABYTES);
        const int kbase = kt * 64 + csw * 8;
#pragma unroll
        for (int t = 0; t < IMN; t++) {          // A: TM rows = IMN windows/wave
            const int w8 = (wid * IMN + t) * 8;
            int rA = min(i0 + w8 + rsub, rowsA - 1);
            gl_lds16(A + (size_t)rA * 256 + kbase, Ad + w8 * 64);
        }
#pragma unroll
        for (int t = 0; t < 4; t++) {            // B: 128 rows = 4 windows/wave
            const int w8 = (wid * 4 + t) * 8;
            int rB = min(j0 + w8 + rsub, rowsB - 1);
            gl_lds16(B + (size_t)rB * 256 + kbase, Bd + w8 * 64);
        }
    };

    stage(0, 0);                                 // prologue
#pragma unroll
    for (int kt = 0; kt < 4; kt++) {
        if (kt < 3) {
            stage((kt + 1) & 1, kt + 1);         // prefetch next tile (other buffer)
            asm volatile("s_waitcnt vmcnt(%0)" :: "n"(NLD) : "memory");  // cur landed
        } else {
            asm volatile("s_waitcnt vmcnt(0)" ::: "memory");
        }
        __builtin_amdgcn_s_barrier();            // all waves: cur tile fully in LDS
        asm volatile("" ::: "memory");           // no ds_read hoists above barrier
        const ushort_t* Ac = (const ushort_t*)(smem + (kt & 1) * (ABYTES + BBYTES));
        const ushort_t* Bc = Ac + ABYTES / 2;    // ushort offset = ABYTES bytes
#pragma unroll
        for (int ks = 0; ks < 2; ks++) {
            const int chb = ks * 4 + quad;
            const int sw = ((chb ^ (r16 & 7))) * 8;
            short8 af[IMN], bfr[4];
#pragma unroll
            for (int im = 0; im < IMN; im++)
                af[im] = *(const short8*)(Ac + (wm * (TM / 2) + im * 16 + r16) * 64 + sw);
#pragma unroll
            for (int jn = 0; jn < 4; jn++)
                bfr[jn] = *(const short8*)(Bc + (wn * 64 + jn * 16 + r16) * 64 + sw);
#pragma unroll
            for (int im = 0; im < IMN; im++)
#pragma unroll
                for (int jn = 0; jn < 4; jn++)
                    acc[im][jn] = __builtin_amdgcn_mfma_f32_16x16x32_bf16(
                        af[im], bfr[jn], acc[im][jn], 0, 0, 0);
        }
        if (kt < 3) {
            // DS queue drain before any wave re-stages this buffer (ISA §8)
            asm volatile("s_waitcnt lgkmcnt(0)" ::: "memory");
            __builtin_amdgcn_sched_barrier(0);
            __builtin_amdgcn_s_barrier();        // reads of cur done -> re-stageable
            asm volatile("" ::: "memory");
        }
    }

    const int rows_lim = rowsA - i0;
    const int cols_lim = rowsB - j0;

    if constexpr (sizeof(TOUT) == 4) {
        // ---- fp32: LDS-transposed epilogue, 32-row chunks, pitch 132 ----
        float* T = (float*)smem;                 // 32*132*4 = 16896 B <= stage area
        constexpr int NCH = TM / 32;
#pragma unroll
        for (int c = 0; c < NCH; c++) {
            const int crow = c * 32;
            __syncthreads();                     // full drain: LDS free for reuse
            if (wm == crow / (TM / 2)) {
                const int imb = (crow - wm * (TM / 2)) / 16;
#pragma unroll
                for (int ii = 0; ii < 2; ii++) {
                    const int im = imb + ii;
#pragma unroll
                    for (int jn = 0; jn < 4; jn++) {
                        const int jl = wn * 64 + jn * 16 + r16;
                        float bj = 0.f;
                        if (!BIAS_I) {
                            int jg = j0 + jl;
                            bj = (jg >= jsplit) ? bias2[jg - jsplit] : bias[jg];
                        }
#pragma unroll
                        for (int r = 0; r < 4; r++) {
                            const int rl = ii * 16 + quad * 4 + r;
                            float bv = BIAS_I ? bias[min(i0 + crow + rl, rowsA - 1)] : bj;
                            T[rl * 132 + jl] = fmaxf(acc[im][jn][r] + bv, 0.f);
                        }
                    }
                }
            }
            __syncthreads();
            const int c4 = tid & 31, rl0 = tid >> 5;
#pragma unroll
            for (int s = 0; s < 4; s++) {
                const int rl = rl0 + s * 8;
                const int il = crow + rl;
                if (il < rows_lim) {
                    const int jl = c4 * 4;
                    float* dst = (float*)C + (size_t)(i0 + il) * rowsB + j0 + jl;
                    if (jl + 4 <= cols_lim) {
                        float4v vv = *(const float4v*)&T[rl * 132 + jl];
                        __builtin_nontemporal_store(vv, (float4v*)dst);
                    } else {
                        for (int jj = 0; jj < 4; jj++)
                            if (jl + jj < cols_lim) dst[jj] = T[rl * 132 + jl + jj];
                    }
                }
            }
        }
    } else {
        // ---- bf16: direct scalar stores (small outputs, re-read next layer) ----
#pragma unroll
        for (int im = 0; im < IMN; im++) {
#pragma unroll
            for (int jn = 0; jn < 4; jn++) {
                const int jl = wn * 64 + jn * 16 + r16;
                if (jl < cols_lim) {
                    float bj = 0.f;
                    if (!BIAS_I) {
                        int jg = j0 + jl;
                        bj = (jg >= jsplit) ? bias2[jg - jsplit] : bias[jg];
                    }
#pragma unroll
                    for (int r = 0; r < 4; r++) {
                        const int il = wm * (TM / 2) + im * 16 + quad * 4 + r;
                        if (il < rows_lim) {
                            float bv = BIAS_I ? bias[i0 + il] : bj;
                            float v = fmaxf(acc[im][jn][r] + bv, 0.f);
                            stv(C + (size_t)(i0 + il) * rowsB + (j0 + jl), v);
                        }
                    }
                }
            }
        }
    }
}

// standalone bf16 GEMMs (non-SWZ GRP=8 M-grouping, exact grid tilesM*tilesN)
template <bool BIAS_I, int TM, typename TOUT>
__global__ __launch_bounds__(256) void gemm_nt_kernel(
    const ushort_t* __restrict__ A, const ushort_t* __restrict__ B,
    const float* __restrict__ bias, const float* __restrict__ bias2, int jsplit,
    TOUT* __restrict__ C, int rowsA, int rowsB, int tilesM, int tilesN) {
    __shared__ __align__(16) char smem[2 * (TM * 128 + 16384)];
    const int lin = blockIdx.x;
    const int GRP = 8;
    const int nig = GRP * tilesN;
    const int gidg = lin / nig;
    const int first_m = gidg * GRP;
    const int gsz = min(tilesM - first_m, GRP);
    const int in_grp = lin - gidg * nig;
    int pid_m = first_m + (in_grp % gsz);
    int pid_n = in_grp / gsz;
    gemm_tile_body<BIAS_I, TM, TOUT>(smem, pid_m, pid_n, A, B, bias, bias2, jsplit,
                                     C, rowsA, rowsB);
}

// Dual fp32 GEMM dispatch: blocks [0,nA) run a2 (TM=64, bias-j), the rest run
// s2 (TM=128, bias-i, 8x8 supergroup + bijective XCD chunk swizzle on LOCAL index;
// the +nA physical offset is a constant shift mod 8, chunk->XCD stays bijective).
__global__ __launch_bounds__(256) void gemm_dual_kernel(
    const ushort_t* __restrict__ Aa, const ushort_t* __restrict__ Ba,
    const float* __restrict__ biasA, float* __restrict__ Ca, int rowsAa,
    const ushort_t* __restrict__ As, const ushort_t* __restrict__ Bs,
    const float* __restrict__ biasS, float* __restrict__ Cs, int rowsS,
    int tilesMs, int nA) {
    __shared__ __align__(16) char smem[65536];
    const int BIG = 1 << 30;
    if ((int)blockIdx.x < nA) {
        // a2 tile: tilesN=1 -> pid_m = blockIdx.x, pid_n = 0
        gemm_tile_body<false, 64, float>(smem, blockIdx.x, 0, Aa, Ba, biasA, nullptr, BIG,
                                         Ca, rowsAa, 128);
    } else {
        const int lin = blockIdx.x - nA;
        const int nwg = gridDim.x - nA;            // tM8*tM8*64, multiple of 64
        const int w = (lin & 7) * (nwg >> 3) + (lin >> 3);   // XCD chunk (bijective)
        const int tM8 = (tilesMs + 7) >> 3;
        const int sg = w >> 6, is = w & 63;        // 8x8 supergroup
        const int sgm = sg % tM8, sgn = sg / tM8;
        const int pid_m = sgm * 8 + (is & 7);
        const int pid_n = sgn * 8 + (is >> 3);
        if (pid_m >= tilesMs || pid_n >= tilesMs) return;   // block-uniform exit
        gemm_tile_body<true, 128, float>(smem, pid_m, pid_n, As, Bs, biasS, nullptr, BIG,
                                         Cs, rowsS, rowsS);
    }
}

// ---------------- host launch ----------------
extern "C" void kernel_launch(void* const* d_in, const int* in_sizes, int n_in,
                              void* d_out, int out_size, void* d_ws, size_t ws_size,
                              hipStream_t stream) {
    const int N = in_sizes[18];       // bl_s2 length == num nodes
    const int E = in_sizes[1] / 2;

    const float* x = (const float*)d_in[0];
    const int* ei = (const int*)d_in[1];
    const int* srcv = ei;
    const int* dstv = ei + E;

    // layer order in inputs: e1, e2, a1, a2, s1, s2
    const float* Wl[6] = {(const float*)d_in[2],  (const float*)d_in[5],
                          (const float*)d_in[8],  (const float*)d_in[11],
                          (const float*)d_in[14], (const float*)d_in[17]};
    const float* bl[6] = {(const float*)d_in[3],  (const float*)d_in[6],
                          (const float*)d_in[9],  (const float*)d_in[12],
                          (const float*)d_in[15], (const float*)d_in[18]};
    const float* Wr[6] = {(const float*)d_in[4],  (const float*)d_in[7],
                          (const float*)d_in[10], (const float*)d_in[13],
                          (const float*)d_in[16], (const float*)d_in[19]};

    char* p = (char*)d_ws;
    auto carve = [&](size_t bytes) -> char* {
        char* q = p;
        p += (bytes + 255) & ~(size_t)255;
        return q;
    };
    int*      cnt    = (int*)carve((size_t)N * 4);
    int*      rowptr = (int*)carve((size_t)(N + 1) * 4);
    int*      cursor = (int*)carve((size_t)N * 4);
    float*    deginv = (float*)carve((size_t)N * 4);
    int*      srcs   = (int*)carve((size_t)E * 4);
    ushort_t* Acat   = (ushort_t*)carve((size_t)N * 256 * 2);
    ushort_t* AcatS  = (ushort_t*)carve((size_t)N * 256 * 2);
    ushort_t* hbA    = (ushort_t*)carve((size_t)N * 128 * 2);   // bf16 activations
    ushort_t* hbB    = (ushort_t*)carve((size_t)N * 128 * 2);
    ushort_t* hbC    = (ushort_t*)carve((size_t)N * 256 * 2);   // a1|s1 fused output
    ushort_t* WTs2   = (ushort_t*)carve((size_t)N * 256 * 2);   // s2 weights transposed
    ushort_t* WsT    = (ushort_t*)carve((size_t)5 * 128 * 256 * 2);

    hipMemsetAsync(cnt, 0, (size_t)N * 4, stream);

    // fused setup: w5 transposes (40 tiles) + ws2 transpose (nbx*4) + hist
    W5 w5;
    w5.W0[0] = Wl[0]; w5.W1[0] = Wr[0];   // e1
    w5.W0[1] = Wl[1]; w5.W1[1] = Wr[1];   // e2
    w5.W0[2] = Wl[2]; w5.W1[2] = Wr[2];   // a1
    w5.W0[3] = Wl[4]; w5.W1[3] = Wr[4];   // s1
    w5.W0[4] = Wl[3]; w5.W1[4] = Wr[3];   // a2
    const int nbx = (N + 63) / 64;
    const int histBlocks = (E + 255) / 256;
    setup_kernel<<<40 + nbx * 4 + histBlocks, 256, 0, stream>>>(
        w5, WsT, Wl[5], Wr[5], WTs2, N, nbx, dstv, cnt, E);
    scan_kernel<<<1, 1024, 0, stream>>>(cnt, rowptr, cursor, deginv, N);
    scatter_kernel<<<(E + 255) / 256, 256, 0, stream>>>(srcv, dstv, cursor, srcs, E);

    float* outp = (float*)d_out;
    float* xh_out = outp + (size_t)N * N;

    const int tM128 = (N + 127) / 128;    // 79  (s2 tiles)
    const int tM64  = (N + 63) / 64;      // 157 (small-GEMM tiles)
    const int BIG = 1 << 30;

    // e1: x(fp32) -> hbA
    aggregate_kernel<float><<<(N + 3) / 4, 256, 0, stream>>>(x, srcs, rowptr, deginv, Acat, N);
    gemm_nt_kernel<false, 64, ushort_t><<<tM64, 256, 0, stream>>>(
        Acat, WsT + 0 * 32768, bl[0], nullptr, BIG, hbA, N, 128, tM64, 1);
    // e2: hbA -> hbB (h)
    aggregate_kernel<ushort_t><<<(N + 3) / 4, 256, 0, stream>>>(hbA, srcs, rowptr, deginv, Acat, N);
    gemm_nt_kernel<false, 64, ushort_t><<<tM64, 256, 0, stream>>>(
        Acat, WsT + 1 * 32768, bl[1], nullptr, BIG, hbB, N, 128, tM64, 1);
    // a1+s1 fused: ONE aggregate of h, ONE GEMM with 256 output cols -> hbC
    aggregate_kernel<ushort_t><<<(N + 3) / 4, 256, 0, stream>>>(hbB, srcs, rowptr, deginv, Acat, N);
    gemm_nt_kernel<false, 64, ushort_t><<<tM64 * 2, 256, 0, stream>>>(
        Acat, WsT + 2 * 32768, bl[2], bl[4], 128, hbC, N, 256, tM64, 2);
    // a2+s2 aggregates fused: one gather pass over hbC -> Acat (a-half), AcatS (s-half)
    aggregate2_kernel<<<(N + 3) / 4, 256, 0, stream>>>(hbC, srcs, rowptr, deginv, Acat, AcatS, N);
    // a2 -> xh and s2 -> outp in ONE dual dispatch
    const int tM8 = (tM128 + 7) / 8;
    gemm_dual_kernel<<<tM64 + tM8 * tM8 * 64, 256, 0, stream>>>(
        Acat, WsT + 4 * 32768, bl[3], xh_out, N,
        WTs2, AcatS, bl[5], outp, N, tM128, tM64);

    (void)n_in; (void)out_size; (void)ws_size;
}